// Round 6
// baseline (834.542 us; speedup 1.0000x reference)
//
#include <hip/hip_runtime.h>
#include <hip/hip_cooperative_groups.h>

namespace cg = cooperative_groups;

#define SEQ_LEN 262144
#define K 512                      // steps per group (one wave per group)
#define M 8                        // steps per lane
#define NG (SEQ_LEN / K)           // 512 groups
#define NITER 10                   // Newton iterations
#define HID 256
#define C2LE 2.885390081777927f    // 2*log2(e)

// ---------- DPP helpers ----------
template <int CTRL, int RM>
__device__ __forceinline__ float dpp_mov(float oldv, float v) {
    return __builtin_bit_cast(float, __builtin_amdgcn_update_dpp(
        __builtin_bit_cast(int, oldv), __builtin_bit_cast(int, v), CTRL, RM, 0xf, false));
}
template <int CTRL, int RM>
__device__ __forceinline__ float dpp_add(float v) {
    return v + dpp_mov<CTRL, RM>(0.0f, v);
}
__device__ __forceinline__ float wave_incl_scan(float v) {
    v = dpp_add<0x111, 0xf>(v);
    v = dpp_add<0x112, 0xf>(v);
    v = dpp_add<0x114, 0xf>(v);
    v = dpp_add<0x118, 0xf>(v);
    v = dpp_add<0x142, 0xa>(v);
    v = dpp_add<0x143, 0xc>(v);
    return v;
}
// full-wave shift right by 1 (lane i <- lane i-1; lane 0 <- 0)
__device__ __forceinline__ float dpp_wshr1(float v) {
    return __builtin_bit_cast(float, __builtin_amdgcn_update_dpp(
        0, __builtin_bit_cast(int, v), 0x138, 0xf, 0xf, false));
}
// full-wave shift left by 1 (lane i <- lane i+1; lane 63 <- 0)
__device__ __forceinline__ float dpp_wshl1(float v) {
    return __builtin_bit_cast(float, __builtin_amdgcn_update_dpp(
        0, __builtin_bit_cast(int, v), 0x130, 0xf, 0xf, false));
}
__device__ __forceinline__ float readlane_f(float v, int lane) {
    return __builtin_bit_cast(
        float, __builtin_amdgcn_readlane(__builtin_bit_cast(int, v), lane));
}

// ---------- affine map (3x3 M, 3 b) ----------
struct Aff { float m[9]; float b[3]; };

// r = n ∘ o  (apply o first, then n)
__device__ __forceinline__ void compose(Aff& r, const Aff& n, const Aff& o) {
#pragma unroll
    for (int i = 0; i < 3; ++i) {
#pragma unroll
        for (int j = 0; j < 3; ++j)
            r.m[3*i+j] = fmaf(n.m[3*i+0], o.m[0+j],
                         fmaf(n.m[3*i+1], o.m[3+j],
                              n.m[3*i+2] * o.m[6+j]));
        r.b[i] = fmaf(n.m[3*i+0], o.b[0],
                 fmaf(n.m[3*i+1], o.b[1],
                 fmaf(n.m[3*i+2], o.b[2], n.b[i])));
    }
}

template <int CTRL, int RM>
__device__ __forceinline__ void scan_level(Aff& a) {
    Aff p;
    p.m[0] = dpp_mov<CTRL, RM>(1.f, a.m[0]);
    p.m[1] = dpp_mov<CTRL, RM>(0.f, a.m[1]);
    p.m[2] = dpp_mov<CTRL, RM>(0.f, a.m[2]);
    p.m[3] = dpp_mov<CTRL, RM>(0.f, a.m[3]);
    p.m[4] = dpp_mov<CTRL, RM>(1.f, a.m[4]);
    p.m[5] = dpp_mov<CTRL, RM>(0.f, a.m[5]);
    p.m[6] = dpp_mov<CTRL, RM>(0.f, a.m[6]);
    p.m[7] = dpp_mov<CTRL, RM>(0.f, a.m[7]);
    p.m[8] = dpp_mov<CTRL, RM>(1.f, a.m[8]);
    p.b[0] = dpp_mov<CTRL, RM>(0.f, a.b[0]);
    p.b[1] = dpp_mov<CTRL, RM>(0.f, a.b[1]);
    p.b[2] = dpp_mov<CTRL, RM>(0.f, a.b[2]);
    Aff r; compose(r, a, p); a = r;
}

// ---------- fused cooperative kernel: vprep + Newton loop + store ----------
__global__ __launch_bounds__(64, 1) void coop_kernel(
    const float* __restrict__ u,   // [3][S]
    const float* __restrict__ Am,  // [3][3]
    const float* __restrict__ dtp, // scalar
    const float* __restrict__ Bm,  // [3][3]
    const float* __restrict__ bAp, // [3]
    float4* __restrict__ jfA,      // [NG*3] ping
    float4* __restrict__ jfB,      // [NG*3] pong
    float* __restrict__ xs) {      // [3][S] membrane out
    const int lane = threadIdx.x;
    const int g = blockIdx.x;
    const float dt = dtp[0];
    const float invdt3 = 1.0f / (3.0f * dt);
    float a[9], as[9];
#pragma unroll
    for (int i = 0; i < 9; ++i) { a[i] = Am[i]; as[i] = C2LE * Am[i]; }

    // ---- one-time: load u slice, build w (C2LE-scaled) in registers ----
    const int base = g * K + M * lane;
    float4 ua0 = *(const float4*)(u + base);
    float4 ua1 = *(const float4*)(u + base + 4);
    float4 ub0 = *(const float4*)(u + SEQ_LEN + base);
    float4 ub1 = *(const float4*)(u + SEQ_LEN + base + 4);
    float4 uc0 = *(const float4*)(u + 2 * SEQ_LEN + base);
    float4 uc1 = *(const float4*)(u + 2 * SEQ_LEN + base + 4);
    float B0 = Bm[0], B1 = Bm[1], B2 = Bm[2], B3 = Bm[3], B4 = Bm[4],
          B5 = Bm[5], B6 = Bm[6], B7 = Bm[7], B8 = Bm[8];
    float ba0 = bAp[0], ba1 = bAp[1], ba2 = bAp[2];
    float U0[M] = { ua0.x, ua0.y, ua0.z, ua0.w, ua1.x, ua1.y, ua1.z, ua1.w };
    float U1[M] = { ub0.x, ub0.y, ub0.z, ub0.w, ub1.x, ub1.y, ub1.z, ub1.w };
    float U2[M] = { uc0.x, uc0.y, uc0.z, uc0.w, uc1.x, uc1.y, uc1.z, uc1.w };
    float w0[M], w1[M], w2[M];
#pragma unroll
    for (int i = 0; i < M; ++i) {
        w0[i] = C2LE * fmaf(B0, U0[i], fmaf(B1, U1[i], fmaf(B2, U2[i], ba0)));
        w1[i] = C2LE * fmaf(B3, U0[i], fmaf(B4, U1[i], fmaf(B5, U2[i], ba1)));
        w2[i] = C2LE * fmaf(B6, U0[i], fmaf(B7, U1[i], fmaf(B8, U2[i], ba2)));
    }

    // ---- replicated group-start states: lane l holds groups 8l..8l+7 ----
    float xh80[M], xh81[M], xh82[M];
#pragma unroll
    for (int i = 0; i < M; ++i) { xh80[i] = 0.f; xh81[i] = 0.f; xh82[i] = 0.f; }

    cg::grid_group grid = cg::this_grid();
    const int sel = g & 7, src = g >> 3;

    for (int it = 0; it <= NITER; ++it) {
        // ---- broadcast this block's start state xh[g] from the replicated set ----
        float p0 = xh80[0], p1 = xh81[0], p2 = xh82[0];
#pragma unroll
        for (int i = 1; i < M; ++i) {
            p0 = (sel == i) ? xh80[i] : p0;
            p1 = (sel == i) ? xh81[i] : p1;
            p2 = (sel == i) ? xh82[i] : p2;
        }
        const float x0 = readlane_f(p0, src);
        const float x1 = readlane_f(p1, src);
        const float x2 = readlane_f(p2, src);

        // ---- shoot body (validated R4/R5 scheme) ----
        float zc0 = fmaf(as[0], x0, fmaf(as[1], x1, as[2] * x2));
        float zc1 = fmaf(as[3], x0, fmaf(as[4], x1, as[5] * x2));
        float zc2 = fmaf(as[6], x0, fmaf(as[7], x1, as[8] * x2));

        float t0s[M][3], c1s[M][3];
        Aff acc;
#pragma unroll
        for (int i = 0; i < M; ++i) {
            float z[3] = { w0[i] + zc0, w1[i] + zc1, w2[i] + zc2 };
            float cb[3], cv[3];
#pragma unroll
            for (int c = 0; c < 3; ++c) {
                float e  = __builtin_amdgcn_exp2f(z[c]);
                float r  = __builtin_amdgcn_rcpf(e + 1.0f);
                float t  = fmaf(-2.0f, r, 1.0f);
                float b  = dt * t;
                float c1 = fmaf(-b, t, dt);
                t0s[i][c] = t; c1s[i][c] = c1;
                cb[c] = b; cv[c] = c1;
            }
            Aff s;
            s.m[0] = fmaf(cv[0], a[0], 1.f); s.m[1] = cv[0] * a[1]; s.m[2] = cv[0] * a[2];
            s.m[3] = cv[1] * a[3]; s.m[4] = fmaf(cv[1], a[4], 1.f); s.m[5] = cv[1] * a[5];
            s.m[6] = cv[2] * a[6]; s.m[7] = cv[2] * a[7]; s.m[8] = fmaf(cv[2], a[8], 1.f);
            s.b[0] = cb[0]; s.b[1] = cb[1]; s.b[2] = cb[2];
            if (i == 0) acc = s;
            else { Aff r; compose(r, s, acc); acc = r; }
        }

        scan_level<0x111, 0xf>(acc);
        scan_level<0x112, 0xf>(acc);
        scan_level<0x114, 0xf>(acc);
        scan_level<0x118, 0xf>(acc);
        scan_level<0x142, 0xa>(acc);
        scan_level<0x143, 0xc>(acc);

        float ds0 = dpp_wshr1(acc.b[0]);
        float ds1 = dpp_wshr1(acc.b[1]);
        float ds2 = dpp_wshr1(acc.b[2]);

        float d0 = ds0, d1 = ds1, d2 = ds2;
        float outv[M][3];
#pragma unroll
        for (int i = 0; i < M; ++i) {
            float zz0 = fmaf(a[0], d0, fmaf(a[1], d1, a[2] * d2));
            float zz1 = fmaf(a[3], d0, fmaf(a[4], d1, a[5] * d2));
            float zz2 = fmaf(a[6], d0, fmaf(a[7], d1, a[8] * d2));
            float zz[3] = { zz0, zz1, zz2 };
            float dd[3];
#pragma unroll
            for (int c = 0; c < 3; ++c) {
                float t   = t0s[i][c], cv = c1s[i][c];
                float cb  = dt * t;
                float cT2 = -(t * cv);
                float pc  = fmaf(-invdt3, cv, 0.66666667f * (t * t));
                float cT3 = cv * pc;
                dd[c] = fmaf(fmaf(fmaf(cT3, zz[c], cT2), zz[c], cv), zz[c], cb);
            }
            d0 += dd[0]; d1 += dd[1]; d2 += dd[2];
            outv[i][0] = d0; outv[i][1] = d1; outv[i][2] = d2;
        }

        float q0 = d0 - acc.b[0], q1 = d1 - acc.b[1], q2 = d2 - acc.b[2];
        float e0 = wave_incl_scan(q0) - q0;
        float e1 = wave_incl_scan(q1) - q1;
        float e2 = wave_incl_scan(q2) - q2;
        float cor0 = x0 + e0, cor1 = x1 + e1, cor2 = x2 + e2;

        if (it == NITER) {
            // ---- final pass: store the trajectory ----
            float4 s0a = { outv[0][0] + cor0, outv[1][0] + cor0, outv[2][0] + cor0, outv[3][0] + cor0 };
            float4 s0b = { outv[4][0] + cor0, outv[5][0] + cor0, outv[6][0] + cor0, outv[7][0] + cor0 };
            float4 s1a = { outv[0][1] + cor1, outv[1][1] + cor1, outv[2][1] + cor1, outv[3][1] + cor1 };
            float4 s1b = { outv[4][1] + cor1, outv[5][1] + cor1, outv[6][1] + cor1, outv[7][1] + cor1 };
            float4 s2a = { outv[0][2] + cor2, outv[1][2] + cor2, outv[2][2] + cor2, outv[3][2] + cor2 };
            float4 s2b = { outv[4][2] + cor2, outv[5][2] + cor2, outv[6][2] + cor2, outv[7][2] + cor2 };
            *(float4*)&xs[base]                   = s0a;
            *(float4*)&xs[base + 4]               = s0b;
            *(float4*)&xs[SEQ_LEN + base]         = s1a;
            *(float4*)&xs[SEQ_LEN + base + 4]     = s1b;
            *(float4*)&xs[2 * SEQ_LEN + base]     = s2a;
            *(float4*)&xs[2 * SEQ_LEN + base + 4] = s2b;
            break;
        }

        // ---- publish J_g, F_g (ping-pong buffer) ----
        float4* jfw = (it & 1) ? jfB : jfA;
        if (lane == 63) {
            float F0 = outv[M-1][0] + cor0;
            float F1 = outv[M-1][1] + cor1;
            float F2 = outv[M-1][2] + cor2;
            jfw[3*g + 0] = float4{ acc.m[0], acc.m[1], acc.m[2], acc.m[3] };
            jfw[3*g + 1] = float4{ acc.m[4], acc.m[5], acc.m[6], acc.m[7] };
            jfw[3*g + 2] = float4{ acc.m[8], F0, F1, F2 };
        }
        __threadfence();
        grid.sync();

        // ---- redundant Newton correct (every block, identical math) ----
        const float4* jfr = (it & 1) ? jfB : jfA;
        float shl0 = dpp_wshl1(xh80[0]);   // xh of next lane's first group
        float shl1 = dpp_wshl1(xh81[0]);
        float shl2 = dpp_wshl1(xh82[0]);
        float J[8][9], dv[8][3];
#pragma unroll
        for (int i = 0; i < 8; ++i) {
            int gg = 8 * lane + i;
            float4 q0v = jfr[3*gg + 0], q1v = jfr[3*gg + 1], q2v = jfr[3*gg + 2];
            J[i][0] = q0v.x; J[i][1] = q0v.y; J[i][2] = q0v.z; J[i][3] = q0v.w;
            J[i][4] = q1v.x; J[i][5] = q1v.y; J[i][6] = q1v.z; J[i][7] = q1v.w;
            J[i][8] = q2v.x;
            float xn0 = (i < 7) ? xh80[i+1] : shl0;
            float xn1 = (i < 7) ? xh81[i+1] : shl1;
            float xn2 = (i < 7) ? xh82[i+1] : shl2;
            dv[i][0] = q2v.y - xn0;
            dv[i][1] = q2v.z - xn1;
            dv[i][2] = q2v.w - xn2;
        }
        Aff c;
#pragma unroll
        for (int k = 0; k < 9; ++k) c.m[k] = J[0][k];
        c.b[0] = dv[0][0]; c.b[1] = dv[0][1]; c.b[2] = dv[0][2];
#pragma unroll
        for (int i = 1; i < 8; ++i) {
            Aff s;
#pragma unroll
            for (int k = 0; k < 9; ++k) s.m[k] = J[i][k];
            s.b[0] = dv[i][0]; s.b[1] = dv[i][1]; s.b[2] = dv[i][2];
            Aff r; compose(r, s, c); c = r;
        }
        scan_level<0x111, 0xf>(c);
        scan_level<0x112, 0xf>(c);
        scan_level<0x114, 0xf>(c);
        scan_level<0x118, 0xf>(c);
        scan_level<0x142, 0xa>(c);
        scan_level<0x143, 0xc>(c);
        float ce0 = dpp_wshr1(c.b[0]);
        float ce1 = dpp_wshr1(c.b[1]);
        float ce2 = dpp_wshr1(c.b[2]);
#pragma unroll
        for (int i = 0; i < 8; ++i) {
            float n0 = fmaf(J[i][0], ce0, fmaf(J[i][1], ce1, fmaf(J[i][2], ce2, dv[i][0])));
            float n1 = fmaf(J[i][3], ce0, fmaf(J[i][4], ce1, fmaf(J[i][5], ce2, dv[i][1])));
            float n2 = fmaf(J[i][6], ce0, fmaf(J[i][7], ce1, fmaf(J[i][8], ce2, dv[i][2])));
            ce0 = n0; ce1 = n1; ce2 = n2;
            if (i < 7) { xh80[i+1] += ce0; xh81[i+1] += ce1; xh82[i+1] += ce2; }
        }
        // boundary 8l comes from lane l-1's last walk value; lane 0 gets +0 (group 0 exact)
        xh80[0] += dpp_wshr1(ce0);
        xh81[0] += dpp_wshr1(ce1);
        xh82[0] += dpp_wshr1(ce2);
    }
}

// ---------- MLP (parallel, full GPU) ----------
__global__ __launch_bounds__(256) void mlp_kernel(
    const float* __restrict__ xs, const float* __restrict__ W1,
    const float* __restrict__ b1v, const float* __restrict__ W2,
    const float* __restrict__ b2v, float* __restrict__ out) {
    int s = blockIdx.x * 256 + threadIdx.x;
    float x0 = xs[s], x1 = xs[SEQ_LEN + s], x2 = xs[2 * SEQ_LEN + s];
    float acc0 = 0.f, acc1 = 0.f, acc2 = 0.f;
#pragma unroll 4
    for (int h = 0; h < HID; ++h) {
        float hv = fmaf(W1[3 * h + 0], x0,
                   fmaf(W1[3 * h + 1], x1,
                   fmaf(W1[3 * h + 2], x2, b1v[h])));
        hv = fmaxf(hv, 0.f);
        acc0 = fmaf(W2[h], hv, acc0);
        acc1 = fmaf(W2[HID + h], hv, acc1);
        acc2 = fmaf(W2[2 * HID + h], hv, acc2);
    }
    out[s] = acc0 + b2v[0];
    out[SEQ_LEN + s] = acc1 + b2v[1];
    out[2 * SEQ_LEN + s] = acc2 + b2v[2];
}

extern "C" void kernel_launch(void* const* d_in, const int* in_sizes, int n_in,
                              void* d_out, int out_size, void* d_ws, size_t ws_size,
                              hipStream_t stream) {
    const float* u  = (const float*)d_in[0];
    const float* dt = (const float*)d_in[1];
    const float* A  = (const float*)d_in[2];
    const float* B  = (const float*)d_in[3];
    const float* bA = (const float*)d_in[4];
    const float* W1 = (const float*)d_in[5];
    const float* b1 = (const float*)d_in[6];
    const float* W2 = (const float*)d_in[7];
    const float* b2 = (const float*)d_in[8];

    float* out  = (float*)d_out;
    float* memb = out + 3 * SEQ_LEN;

    float4* jfA = (float4*)d_ws;        // [NG*3] 24.6 KB
    float4* jfB = jfA + 3 * NG;         // [NG*3] 24.6 KB

    void* args[] = { (void*)&u, (void*)&A, (void*)&dt, (void*)&B, (void*)&bA,
                     (void*)&jfA, (void*)&jfB, (void*)&memb };
    hipLaunchCooperativeKernel((void*)coop_kernel, dim3(NG), dim3(64),
                               args, 0, stream);
    mlp_kernel<<<SEQ_LEN / 256, 256, 0, stream>>>(memb, W1, b1, W2, b2, out);
}

// Round 7
// 157.213 us; speedup vs baseline: 5.3083x; 5.3083x over previous
//
#include <hip/hip_runtime.h>

#define SEQ_LEN 262144
#define K 512                      // steps per group (one wave per group)
#define M 8                        // steps per lane
#define NG (SEQ_LEN / K)           // 512 groups
#define NCORR 8                    // Newton corrections (R5 used 10; quad. convergence)
#define HID 256
#define C2LE 2.885390081777927f    // 2*log2(e)

// ---------- DPP helpers ----------
template <int CTRL, int RM>
__device__ __forceinline__ float dpp_mov(float oldv, float v) {
    return __builtin_bit_cast(float, __builtin_amdgcn_update_dpp(
        __builtin_bit_cast(int, oldv), __builtin_bit_cast(int, v), CTRL, RM, 0xf, false));
}
template <int CTRL, int RM>
__device__ __forceinline__ float dpp_add(float v) {
    return v + dpp_mov<CTRL, RM>(0.0f, v);
}
__device__ __forceinline__ float wave_incl_scan(float v) {
    v = dpp_add<0x111, 0xf>(v);
    v = dpp_add<0x112, 0xf>(v);
    v = dpp_add<0x114, 0xf>(v);
    v = dpp_add<0x118, 0xf>(v);
    v = dpp_add<0x142, 0xa>(v);
    v = dpp_add<0x143, 0xc>(v);
    return v;
}
// full-wave shift right by 1 (lane i <- lane i-1; lane 0 <- 0)
__device__ __forceinline__ float dpp_wshr1(float v) {
    return __builtin_bit_cast(float, __builtin_amdgcn_update_dpp(
        0, __builtin_bit_cast(int, v), 0x138, 0xf, 0xf, false));
}
__device__ __forceinline__ float readlane_f(float v, int lane) {
    return __builtin_bit_cast(
        float, __builtin_amdgcn_readlane(__builtin_bit_cast(int, v), lane));
}

// ---------- affine map (3x3 M, 3 b) ----------
struct Aff { float m[9]; float b[3]; };

// r = n ∘ o  (apply o first, then n)
__device__ __forceinline__ void compose(Aff& r, const Aff& n, const Aff& o) {
#pragma unroll
    for (int i = 0; i < 3; ++i) {
#pragma unroll
        for (int j = 0; j < 3; ++j)
            r.m[3*i+j] = fmaf(n.m[3*i+0], o.m[0+j],
                         fmaf(n.m[3*i+1], o.m[3+j],
                              n.m[3*i+2] * o.m[6+j]));
        r.b[i] = fmaf(n.m[3*i+0], o.b[0],
                 fmaf(n.m[3*i+1], o.b[1],
                 fmaf(n.m[3*i+2], o.b[2], n.b[i])));
    }
}

template <int CTRL, int RM>
__device__ __forceinline__ void scan_level(Aff& a) {
    Aff p;
    p.m[0] = dpp_mov<CTRL, RM>(1.f, a.m[0]);
    p.m[1] = dpp_mov<CTRL, RM>(0.f, a.m[1]);
    p.m[2] = dpp_mov<CTRL, RM>(0.f, a.m[2]);
    p.m[3] = dpp_mov<CTRL, RM>(0.f, a.m[3]);
    p.m[4] = dpp_mov<CTRL, RM>(1.f, a.m[4]);
    p.m[5] = dpp_mov<CTRL, RM>(0.f, a.m[5]);
    p.m[6] = dpp_mov<CTRL, RM>(0.f, a.m[6]);
    p.m[7] = dpp_mov<CTRL, RM>(0.f, a.m[7]);
    p.m[8] = dpp_mov<CTRL, RM>(1.f, a.m[8]);
    p.b[0] = dpp_mov<CTRL, RM>(0.f, a.b[0]);
    p.b[1] = dpp_mov<CTRL, RM>(0.f, a.b[1]);
    p.b[2] = dpp_mov<CTRL, RM>(0.f, a.b[2]);
    Aff r; compose(r, a, p); a = r;
}

// MODE: 0 = FIRST (xh=0, no correct), 1 = MID (correct+shoot), 2 = STORE (correct+shoot+store)
template <int MODE>
__global__ __launch_bounds__(64) void shootk(
    const float* __restrict__ u,     // [3][S]
    const float* __restrict__ Am,    // [3][3]
    const float* __restrict__ dtp,   // scalar
    const float* __restrict__ Bm,    // [3][3]
    const float* __restrict__ bAp,   // [3]
    const float4* __restrict__ jf_r, // [NG*3] prev iteration's {J,F}
    float4* __restrict__ jf_w,       // [NG*3] this iteration's {J,F}
    float4* __restrict__ xh,         // [NG] group start states
    float* __restrict__ xs) {        // [3][S] membrane out
    const int lane = threadIdx.x;
    const int g = blockIdx.x;
    const float dt = dtp[0];
    const float invdt3 = 1.0f / (3.0f * dt);
    float a[9], as[9];
#pragma unroll
    for (int i = 0; i < 9; ++i) { a[i] = Am[i]; as[i] = C2LE * Am[i]; }

    // ---- build w for this block's slice in registers (from u) ----
    const int base = g * K + M * lane;
    float4 ua0 = *(const float4*)(u + base);
    float4 ua1 = *(const float4*)(u + base + 4);
    float4 ub0 = *(const float4*)(u + SEQ_LEN + base);
    float4 ub1 = *(const float4*)(u + SEQ_LEN + base + 4);
    float4 uc0 = *(const float4*)(u + 2 * SEQ_LEN + base);
    float4 uc1 = *(const float4*)(u + 2 * SEQ_LEN + base + 4);
    float B0 = Bm[0], B1 = Bm[1], B2 = Bm[2], B3 = Bm[3], B4 = Bm[4],
          B5 = Bm[5], B6 = Bm[6], B7 = Bm[7], B8 = Bm[8];
    float ba0 = bAp[0], ba1 = bAp[1], ba2 = bAp[2];
    float U0[M] = { ua0.x, ua0.y, ua0.z, ua0.w, ua1.x, ua1.y, ua1.z, ua1.w };
    float U1[M] = { ub0.x, ub0.y, ub0.z, ub0.w, ub1.x, ub1.y, ub1.z, ub1.w };
    float U2[M] = { uc0.x, uc0.y, uc0.z, uc0.w, uc1.x, uc1.y, uc1.z, uc1.w };
    float w0[M], w1[M], w2[M];
#pragma unroll
    for (int i = 0; i < M; ++i) {
        w0[i] = C2LE * fmaf(B0, U0[i], fmaf(B1, U1[i], fmaf(B2, U2[i], ba0)));
        w1[i] = C2LE * fmaf(B3, U0[i], fmaf(B4, U1[i], fmaf(B5, U2[i], ba1)));
        w2[i] = C2LE * fmaf(B6, U0[i], fmaf(B7, U1[i], fmaf(B8, U2[i], ba2)));
    }

    // ---- Newton correct (redundant per block) -> this block's start state ----
    float x0 = 0.f, x1 = 0.f, x2 = 0.f;
    if (MODE != 0) {
        float J[8][9], dv[8][3], xhn0[8], xhn1[8], xhn2[8];
#pragma unroll
        for (int i = 0; i < 8; ++i) {
            int gg = 8 * lane + i;
            float4 q0v = jf_r[3*gg + 0], q1v = jf_r[3*gg + 1], q2v = jf_r[3*gg + 2];
            J[i][0] = q0v.x; J[i][1] = q0v.y; J[i][2] = q0v.z; J[i][3] = q0v.w;
            J[i][4] = q1v.x; J[i][5] = q1v.y; J[i][6] = q1v.z; J[i][7] = q1v.w;
            J[i][8] = q2v.x;
            float xn0 = 0.f, xn1 = 0.f, xn2 = 0.f;
            if (gg < NG - 1) {                     // xh[gg+1]; group 511's end unused
                float4 xnv = xh[gg + 1];
                xn0 = xnv.x; xn1 = xnv.y; xn2 = xnv.z;
            }
            xhn0[i] = xn0; xhn1[i] = xn1; xhn2[i] = xn2;
            dv[i][0] = q2v.y - xn0;                // F_g - xh_old[g+1]
            dv[i][1] = q2v.z - xn1;
            dv[i][2] = q2v.w - xn2;
        }
        Aff c;
#pragma unroll
        for (int k = 0; k < 9; ++k) c.m[k] = J[0][k];
        c.b[0] = dv[0][0]; c.b[1] = dv[0][1]; c.b[2] = dv[0][2];
#pragma unroll
        for (int i = 1; i < 8; ++i) {
            Aff s;
#pragma unroll
            for (int k = 0; k < 9; ++k) s.m[k] = J[i][k];
            s.b[0] = dv[i][0]; s.b[1] = dv[i][1]; s.b[2] = dv[i][2];
            Aff r; compose(r, s, c); c = r;
        }
        scan_level<0x111, 0xf>(c);
        scan_level<0x112, 0xf>(c);
        scan_level<0x114, 0xf>(c);
        scan_level<0x118, 0xf>(c);
        scan_level<0x142, 0xa>(c);
        scan_level<0x143, 0xc>(c);
        float ce0 = dpp_wshr1(c.b[0]);             // e at group 8*lane
        float ce1 = dpp_wshr1(c.b[1]);
        float ce2 = dpp_wshr1(c.b[2]);
        // walk: e_{g+1} = d_g + J_g e_g ; xh_new[g+1] = xh_old[g+1] + e_{g+1}
#pragma unroll
        for (int i = 0; i < 8; ++i) {
            float n0 = fmaf(J[i][0], ce0, fmaf(J[i][1], ce1, fmaf(J[i][2], ce2, dv[i][0])));
            float n1 = fmaf(J[i][3], ce0, fmaf(J[i][4], ce1, fmaf(J[i][5], ce2, dv[i][1])));
            float n2 = fmaf(J[i][6], ce0, fmaf(J[i][7], ce1, fmaf(J[i][8], ce2, dv[i][2])));
            ce0 = n0; ce1 = n1; ce2 = n2;
            xhn0[i] += ce0; xhn1[i] += ce1; xhn2[i] += ce2;  // now xh_new[8l+i+1]
        }
        // broadcast xh_new[g] to the whole wave (g>0; g==0 stays 0)
        if (g > 0) {
            const int tl = (g - 1) >> 3, idx = (g - 1) & 7;  // wave-uniform
            float p0 = xhn0[0], p1 = xhn1[0], p2 = xhn2[0];
#pragma unroll
            for (int i = 1; i < 8; ++i) {
                p0 = (idx == i) ? xhn0[i] : p0;
                p1 = (idx == i) ? xhn1[i] : p1;
                p2 = (idx == i) ? xhn2[i] : p2;
            }
            x0 = readlane_f(p0, tl);
            x1 = readlane_f(p1, tl);
            x2 = readlane_f(p2, tl);
        }
    }
    // publish this block's (possibly updated) start state for the next correct
    if (MODE != 2 && lane == 0) xh[g] = float4{ x0, x1, x2, 0.f };

    // ---- shoot body (validated scheme) ----
    float zc0 = fmaf(as[0], x0, fmaf(as[1], x1, as[2] * x2));
    float zc1 = fmaf(as[3], x0, fmaf(as[4], x1, as[5] * x2));
    float zc2 = fmaf(as[6], x0, fmaf(as[7], x1, as[8] * x2));

    float t0s[M][3], c1s[M][3];
    Aff acc;
#pragma unroll
    for (int i = 0; i < M; ++i) {
        float z[3] = { w0[i] + zc0, w1[i] + zc1, w2[i] + zc2 };
        float cb[3], cv[3];
#pragma unroll
        for (int c = 0; c < 3; ++c) {
            float e  = __builtin_amdgcn_exp2f(z[c]);
            float r  = __builtin_amdgcn_rcpf(e + 1.0f);
            float t  = fmaf(-2.0f, r, 1.0f);
            float b  = dt * t;
            float c1 = fmaf(-b, t, dt);
            t0s[i][c] = t; c1s[i][c] = c1;
            cb[c] = b; cv[c] = c1;
        }
        Aff s;
        s.m[0] = fmaf(cv[0], a[0], 1.f); s.m[1] = cv[0] * a[1]; s.m[2] = cv[0] * a[2];
        s.m[3] = cv[1] * a[3]; s.m[4] = fmaf(cv[1], a[4], 1.f); s.m[5] = cv[1] * a[5];
        s.m[6] = cv[2] * a[6]; s.m[7] = cv[2] * a[7]; s.m[8] = fmaf(cv[2], a[8], 1.f);
        s.b[0] = cb[0]; s.b[1] = cb[1]; s.b[2] = cb[2];
        if (i == 0) acc = s;
        else { Aff r; compose(r, s, acc); acc = r; }
    }

    scan_level<0x111, 0xf>(acc);
    scan_level<0x112, 0xf>(acc);
    scan_level<0x114, 0xf>(acc);
    scan_level<0x118, 0xf>(acc);
    scan_level<0x142, 0xa>(acc);
    scan_level<0x143, 0xc>(acc);

    float ds0 = dpp_wshr1(acc.b[0]);
    float ds1 = dpp_wshr1(acc.b[1]);
    float ds2 = dpp_wshr1(acc.b[2]);

    float d0 = ds0, d1 = ds1, d2 = ds2;
    float outv[M][3];
#pragma unroll
    for (int i = 0; i < M; ++i) {
        float zz0 = fmaf(a[0], d0, fmaf(a[1], d1, a[2] * d2));
        float zz1 = fmaf(a[3], d0, fmaf(a[4], d1, a[5] * d2));
        float zz2 = fmaf(a[6], d0, fmaf(a[7], d1, a[8] * d2));
        float zz[3] = { zz0, zz1, zz2 };
        float dd[3];
#pragma unroll
        for (int c = 0; c < 3; ++c) {
            float t   = t0s[i][c], cv = c1s[i][c];
            float cb  = dt * t;
            float cT2 = -(t * cv);
            float pc  = fmaf(-invdt3, cv, 0.66666667f * (t * t));
            float cT3 = cv * pc;
            dd[c] = fmaf(fmaf(fmaf(cT3, zz[c], cT2), zz[c], cv), zz[c], cb);
        }
        d0 += dd[0]; d1 += dd[1]; d2 += dd[2];
        outv[i][0] = d0; outv[i][1] = d1; outv[i][2] = d2;
    }

    float q0 = d0 - acc.b[0], q1 = d1 - acc.b[1], q2 = d2 - acc.b[2];
    float e0 = wave_incl_scan(q0) - q0;
    float e1 = wave_incl_scan(q1) - q1;
    float e2 = wave_incl_scan(q2) - q2;
    float cor0 = x0 + e0, cor1 = x1 + e1, cor2 = x2 + e2;

    if (MODE == 2) {
        float4 s0a = { outv[0][0] + cor0, outv[1][0] + cor0, outv[2][0] + cor0, outv[3][0] + cor0 };
        float4 s0b = { outv[4][0] + cor0, outv[5][0] + cor0, outv[6][0] + cor0, outv[7][0] + cor0 };
        float4 s1a = { outv[0][1] + cor1, outv[1][1] + cor1, outv[2][1] + cor1, outv[3][1] + cor1 };
        float4 s1b = { outv[4][1] + cor1, outv[5][1] + cor1, outv[6][1] + cor1, outv[7][1] + cor1 };
        float4 s2a = { outv[0][2] + cor2, outv[1][2] + cor2, outv[2][2] + cor2, outv[3][2] + cor2 };
        float4 s2b = { outv[4][2] + cor2, outv[5][2] + cor2, outv[6][2] + cor2, outv[7][2] + cor2 };
        *(float4*)&xs[base]                   = s0a;
        *(float4*)&xs[base + 4]               = s0b;
        *(float4*)&xs[SEQ_LEN + base]         = s1a;
        *(float4*)&xs[SEQ_LEN + base + 4]     = s1b;
        *(float4*)&xs[2 * SEQ_LEN + base]     = s2a;
        *(float4*)&xs[2 * SEQ_LEN + base + 4] = s2b;
    } else {
        if (lane == 63) {
            float F0 = outv[M-1][0] + cor0;
            float F1 = outv[M-1][1] + cor1;
            float F2 = outv[M-1][2] + cor2;
            jf_w[3*g + 0] = float4{ acc.m[0], acc.m[1], acc.m[2], acc.m[3] };
            jf_w[3*g + 1] = float4{ acc.m[4], acc.m[5], acc.m[6], acc.m[7] };
            jf_w[3*g + 2] = float4{ acc.m[8], F0, F1, F2 };
        }
    }
}

// ---------- MLP (parallel, full GPU) ----------
__global__ __launch_bounds__(256) void mlp_kernel(
    const float* __restrict__ xs, const float* __restrict__ W1,
    const float* __restrict__ b1v, const float* __restrict__ W2,
    const float* __restrict__ b2v, float* __restrict__ out) {
    int s = blockIdx.x * 256 + threadIdx.x;
    float x0 = xs[s], x1 = xs[SEQ_LEN + s], x2 = xs[2 * SEQ_LEN + s];
    float acc0 = 0.f, acc1 = 0.f, acc2 = 0.f;
#pragma unroll 4
    for (int h = 0; h < HID; ++h) {
        float hv = fmaf(W1[3 * h + 0], x0,
                   fmaf(W1[3 * h + 1], x1,
                   fmaf(W1[3 * h + 2], x2, b1v[h])));
        hv = fmaxf(hv, 0.f);
        acc0 = fmaf(W2[h], hv, acc0);
        acc1 = fmaf(W2[HID + h], hv, acc1);
        acc2 = fmaf(W2[2 * HID + h], hv, acc2);
    }
    out[s] = acc0 + b2v[0];
    out[SEQ_LEN + s] = acc1 + b2v[1];
    out[2 * SEQ_LEN + s] = acc2 + b2v[2];
}

extern "C" void kernel_launch(void* const* d_in, const int* in_sizes, int n_in,
                              void* d_out, int out_size, void* d_ws, size_t ws_size,
                              hipStream_t stream) {
    const float* u  = (const float*)d_in[0];
    const float* dt = (const float*)d_in[1];
    const float* A  = (const float*)d_in[2];
    const float* B  = (const float*)d_in[3];
    const float* bA = (const float*)d_in[4];
    const float* W1 = (const float*)d_in[5];
    const float* b1 = (const float*)d_in[6];
    const float* W2 = (const float*)d_in[7];
    const float* b2 = (const float*)d_in[8];

    float* out  = (float*)d_out;
    float* memb = out + 3 * SEQ_LEN;

    float4* jfA = (float4*)d_ws;        // [NG*3] 24.6 KB
    float4* jfB = jfA + 3 * NG;         // [NG*3] 24.6 KB
    float4* xh  = jfB + 3 * NG;         // [NG]    8.2 KB

    // first shoot from xh=0 (writes jfA and xh=0)
    shootk<0><<<NG, 64, 0, stream>>>(u, A, dt, B, bA, nullptr, jfA, xh, nullptr);
    // NCORR-1 mid iterations: correct (from jf_r, xh) then shoot (to jf_w, xh)
    float4* rd = jfA;
    float4* wr = jfB;
    for (int j = 1; j < NCORR; ++j) {
        shootk<1><<<NG, 64, 0, stream>>>(u, A, dt, B, bA, rd, wr, xh, nullptr);
        float4* t = rd; rd = wr; wr = t;
    }
    // final: correct + shoot + store trajectory
    shootk<2><<<NG, 64, 0, stream>>>(u, A, dt, B, bA, rd, nullptr, xh, memb);
    mlp_kernel<<<SEQ_LEN / 256, 256, 0, stream>>>(memb, W1, b1, W2, b2, out);
}

// Round 8
// 128.624 us; speedup vs baseline: 6.4882x; 1.2223x over previous
//
#include <hip/hip_runtime.h>

#define SEQ_LEN 262144
#define K 512                      // steps per group (one wave per group)
#define M 8                        // steps per lane
#define NG (SEQ_LEN / K)           // 512 groups
#define NCORR 4                    // Newton corrections (R7: 8 was past convergence)
#define HID 256
#define C2LE 2.885390081777927f    // 2*log2(e)

// ---------- DPP helpers ----------
template <int CTRL, int RM>
__device__ __forceinline__ float dpp_mov(float oldv, float v) {
    return __builtin_bit_cast(float, __builtin_amdgcn_update_dpp(
        __builtin_bit_cast(int, oldv), __builtin_bit_cast(int, v), CTRL, RM, 0xf, false));
}
template <int CTRL, int RM>
__device__ __forceinline__ float dpp_add(float v) {
    return v + dpp_mov<CTRL, RM>(0.0f, v);
}
__device__ __forceinline__ float wave_incl_scan(float v) {
    v = dpp_add<0x111, 0xf>(v);
    v = dpp_add<0x112, 0xf>(v);
    v = dpp_add<0x114, 0xf>(v);
    v = dpp_add<0x118, 0xf>(v);
    v = dpp_add<0x142, 0xa>(v);
    v = dpp_add<0x143, 0xc>(v);
    return v;
}
// full-wave shift right by 1 (lane i <- lane i-1; lane 0 <- 0)
__device__ __forceinline__ float dpp_wshr1(float v) {
    return __builtin_bit_cast(float, __builtin_amdgcn_update_dpp(
        0, __builtin_bit_cast(int, v), 0x138, 0xf, 0xf, false));
}
__device__ __forceinline__ float readlane_f(float v, int lane) {
    return __builtin_bit_cast(
        float, __builtin_amdgcn_readlane(__builtin_bit_cast(int, v), lane));
}

// ---------- affine map (3x3 M, 3 b) ----------
struct Aff { float m[9]; float b[3]; };

// r = n ∘ o  (apply o first, then n)
__device__ __forceinline__ void compose(Aff& r, const Aff& n, const Aff& o) {
#pragma unroll
    for (int i = 0; i < 3; ++i) {
#pragma unroll
        for (int j = 0; j < 3; ++j)
            r.m[3*i+j] = fmaf(n.m[3*i+0], o.m[0+j],
                         fmaf(n.m[3*i+1], o.m[3+j],
                              n.m[3*i+2] * o.m[6+j]));
        r.b[i] = fmaf(n.m[3*i+0], o.b[0],
                 fmaf(n.m[3*i+1], o.b[1],
                 fmaf(n.m[3*i+2], o.b[2], n.b[i])));
    }
}

template <int CTRL, int RM>
__device__ __forceinline__ void scan_level(Aff& a) {
    Aff p;
    p.m[0] = dpp_mov<CTRL, RM>(1.f, a.m[0]);
    p.m[1] = dpp_mov<CTRL, RM>(0.f, a.m[1]);
    p.m[2] = dpp_mov<CTRL, RM>(0.f, a.m[2]);
    p.m[3] = dpp_mov<CTRL, RM>(0.f, a.m[3]);
    p.m[4] = dpp_mov<CTRL, RM>(1.f, a.m[4]);
    p.m[5] = dpp_mov<CTRL, RM>(0.f, a.m[5]);
    p.m[6] = dpp_mov<CTRL, RM>(0.f, a.m[6]);
    p.m[7] = dpp_mov<CTRL, RM>(0.f, a.m[7]);
    p.m[8] = dpp_mov<CTRL, RM>(1.f, a.m[8]);
    p.b[0] = dpp_mov<CTRL, RM>(0.f, a.b[0]);
    p.b[1] = dpp_mov<CTRL, RM>(0.f, a.b[1]);
    p.b[2] = dpp_mov<CTRL, RM>(0.f, a.b[2]);
    Aff r; compose(r, a, p); a = r;
}

// MODE: 0 = FIRST (xh=0, no correct), 1 = MID (correct+shoot), 2 = STORE (correct+shoot+store)
template <int MODE>
__global__ __launch_bounds__(64) void shootk(
    const float* __restrict__ u,     // [3][S]
    const float* __restrict__ Am,    // [3][3]
    const float* __restrict__ dtp,   // scalar
    const float* __restrict__ Bm,    // [3][3]
    const float* __restrict__ bAp,   // [3]
    const float4* __restrict__ jf_r, // [NG*3] prev iteration's {J,F}
    float4* __restrict__ jf_w,       // [NG*3] this iteration's {J,F}
    float4* __restrict__ xh,         // [NG] group start states
    float* __restrict__ xs) {        // [3][S] membrane out
    const int lane = threadIdx.x;
    const int g = blockIdx.x;
    const float dt = dtp[0];
    const float invdt3 = 1.0f / (3.0f * dt);
    float a[9], as[9];
#pragma unroll
    for (int i = 0; i < 9; ++i) { a[i] = Am[i]; as[i] = C2LE * Am[i]; }

    // ---- build w for this block's slice in registers (from u) ----
    const int base = g * K + M * lane;
    float4 ua0 = *(const float4*)(u + base);
    float4 ua1 = *(const float4*)(u + base + 4);
    float4 ub0 = *(const float4*)(u + SEQ_LEN + base);
    float4 ub1 = *(const float4*)(u + SEQ_LEN + base + 4);
    float4 uc0 = *(const float4*)(u + 2 * SEQ_LEN + base);
    float4 uc1 = *(const float4*)(u + 2 * SEQ_LEN + base + 4);
    float B0 = Bm[0], B1 = Bm[1], B2 = Bm[2], B3 = Bm[3], B4 = Bm[4],
          B5 = Bm[5], B6 = Bm[6], B7 = Bm[7], B8 = Bm[8];
    float ba0 = bAp[0], ba1 = bAp[1], ba2 = bAp[2];
    float U0[M] = { ua0.x, ua0.y, ua0.z, ua0.w, ua1.x, ua1.y, ua1.z, ua1.w };
    float U1[M] = { ub0.x, ub0.y, ub0.z, ub0.w, ub1.x, ub1.y, ub1.z, ub1.w };
    float U2[M] = { uc0.x, uc0.y, uc0.z, uc0.w, uc1.x, uc1.y, uc1.z, uc1.w };
    float w0[M], w1[M], w2[M];
#pragma unroll
    for (int i = 0; i < M; ++i) {
        w0[i] = C2LE * fmaf(B0, U0[i], fmaf(B1, U1[i], fmaf(B2, U2[i], ba0)));
        w1[i] = C2LE * fmaf(B3, U0[i], fmaf(B4, U1[i], fmaf(B5, U2[i], ba1)));
        w2[i] = C2LE * fmaf(B6, U0[i], fmaf(B7, U1[i], fmaf(B8, U2[i], ba2)));
    }

    // ---- Newton correct (redundant per block) -> this block's start state ----
    float x0 = 0.f, x1 = 0.f, x2 = 0.f;
    if (MODE != 0) {
        float J[8][9], dv[8][3], xhn0[8], xhn1[8], xhn2[8];
#pragma unroll
        for (int i = 0; i < 8; ++i) {
            int gg = 8 * lane + i;
            float4 q0v = jf_r[3*gg + 0], q1v = jf_r[3*gg + 1], q2v = jf_r[3*gg + 2];
            J[i][0] = q0v.x; J[i][1] = q0v.y; J[i][2] = q0v.z; J[i][3] = q0v.w;
            J[i][4] = q1v.x; J[i][5] = q1v.y; J[i][6] = q1v.z; J[i][7] = q1v.w;
            J[i][8] = q2v.x;
            float xn0 = 0.f, xn1 = 0.f, xn2 = 0.f;
            if (gg < NG - 1) {                     // xh[gg+1]; group 511's end unused
                float4 xnv = xh[gg + 1];
                xn0 = xnv.x; xn1 = xnv.y; xn2 = xnv.z;
            }
            xhn0[i] = xn0; xhn1[i] = xn1; xhn2[i] = xn2;
            dv[i][0] = q2v.y - xn0;                // F_g - xh_old[g+1]
            dv[i][1] = q2v.z - xn1;
            dv[i][2] = q2v.w - xn2;
        }
        Aff c;
#pragma unroll
        for (int k = 0; k < 9; ++k) c.m[k] = J[0][k];
        c.b[0] = dv[0][0]; c.b[1] = dv[0][1]; c.b[2] = dv[0][2];
#pragma unroll
        for (int i = 1; i < 8; ++i) {
            Aff s;
#pragma unroll
            for (int k = 0; k < 9; ++k) s.m[k] = J[i][k];
            s.b[0] = dv[i][0]; s.b[1] = dv[i][1]; s.b[2] = dv[i][2];
            Aff r; compose(r, s, c); c = r;
        }
        scan_level<0x111, 0xf>(c);
        scan_level<0x112, 0xf>(c);
        scan_level<0x114, 0xf>(c);
        scan_level<0x118, 0xf>(c);
        scan_level<0x142, 0xa>(c);
        scan_level<0x143, 0xc>(c);
        float ce0 = dpp_wshr1(c.b[0]);             // e at group 8*lane
        float ce1 = dpp_wshr1(c.b[1]);
        float ce2 = dpp_wshr1(c.b[2]);
        // walk: e_{g+1} = d_g + J_g e_g ; xh_new[g+1] = xh_old[g+1] + e_{g+1}
#pragma unroll
        for (int i = 0; i < 8; ++i) {
            float n0 = fmaf(J[i][0], ce0, fmaf(J[i][1], ce1, fmaf(J[i][2], ce2, dv[i][0])));
            float n1 = fmaf(J[i][3], ce0, fmaf(J[i][4], ce1, fmaf(J[i][5], ce2, dv[i][1])));
            float n2 = fmaf(J[i][6], ce0, fmaf(J[i][7], ce1, fmaf(J[i][8], ce2, dv[i][2])));
            ce0 = n0; ce1 = n1; ce2 = n2;
            xhn0[i] += ce0; xhn1[i] += ce1; xhn2[i] += ce2;  // now xh_new[8l+i+1]
        }
        // broadcast xh_new[g] to the whole wave (g>0; g==0 stays 0)
        if (g > 0) {
            const int tl = (g - 1) >> 3, idx = (g - 1) & 7;  // wave-uniform
            float p0 = xhn0[0], p1 = xhn1[0], p2 = xhn2[0];
#pragma unroll
            for (int i = 1; i < 8; ++i) {
                p0 = (idx == i) ? xhn0[i] : p0;
                p1 = (idx == i) ? xhn1[i] : p1;
                p2 = (idx == i) ? xhn2[i] : p2;
            }
            x0 = readlane_f(p0, tl);
            x1 = readlane_f(p1, tl);
            x2 = readlane_f(p2, tl);
        }
    }
    // publish this block's (possibly updated) start state for the next correct
    if (MODE != 2 && lane == 0) xh[g] = float4{ x0, x1, x2, 0.f };

    // ---- shoot body (validated scheme) ----
    float zc0 = fmaf(as[0], x0, fmaf(as[1], x1, as[2] * x2));
    float zc1 = fmaf(as[3], x0, fmaf(as[4], x1, as[5] * x2));
    float zc2 = fmaf(as[6], x0, fmaf(as[7], x1, as[8] * x2));

    float t0s[M][3], c1s[M][3];
    Aff acc;
#pragma unroll
    for (int i = 0; i < M; ++i) {
        float z[3] = { w0[i] + zc0, w1[i] + zc1, w2[i] + zc2 };
        float cb[3], cv[3];
#pragma unroll
        for (int c = 0; c < 3; ++c) {
            float e  = __builtin_amdgcn_exp2f(z[c]);
            float r  = __builtin_amdgcn_rcpf(e + 1.0f);
            float t  = fmaf(-2.0f, r, 1.0f);
            float b  = dt * t;
            float c1 = fmaf(-b, t, dt);
            t0s[i][c] = t; c1s[i][c] = c1;
            cb[c] = b; cv[c] = c1;
        }
        Aff s;
        s.m[0] = fmaf(cv[0], a[0], 1.f); s.m[1] = cv[0] * a[1]; s.m[2] = cv[0] * a[2];
        s.m[3] = cv[1] * a[3]; s.m[4] = fmaf(cv[1], a[4], 1.f); s.m[5] = cv[1] * a[5];
        s.m[6] = cv[2] * a[6]; s.m[7] = cv[2] * a[7]; s.m[8] = fmaf(cv[2], a[8], 1.f);
        s.b[0] = cb[0]; s.b[1] = cb[1]; s.b[2] = cb[2];
        if (i == 0) acc = s;
        else { Aff r; compose(r, s, acc); acc = r; }
    }

    scan_level<0x111, 0xf>(acc);
    scan_level<0x112, 0xf>(acc);
    scan_level<0x114, 0xf>(acc);
    scan_level<0x118, 0xf>(acc);
    scan_level<0x142, 0xa>(acc);
    scan_level<0x143, 0xc>(acc);

    float ds0 = dpp_wshr1(acc.b[0]);
    float ds1 = dpp_wshr1(acc.b[1]);
    float ds2 = dpp_wshr1(acc.b[2]);

    float d0 = ds0, d1 = ds1, d2 = ds2;
    float outv[M][3];
#pragma unroll
    for (int i = 0; i < M; ++i) {
        float zz0 = fmaf(a[0], d0, fmaf(a[1], d1, a[2] * d2));
        float zz1 = fmaf(a[3], d0, fmaf(a[4], d1, a[5] * d2));
        float zz2 = fmaf(a[6], d0, fmaf(a[7], d1, a[8] * d2));
        float zz[3] = { zz0, zz1, zz2 };
        float dd[3];
#pragma unroll
        for (int c = 0; c < 3; ++c) {
            float t   = t0s[i][c], cv = c1s[i][c];
            float cb  = dt * t;
            float cT2 = -(t * cv);
            float pc  = fmaf(-invdt3, cv, 0.66666667f * (t * t));
            float cT3 = cv * pc;
            dd[c] = fmaf(fmaf(fmaf(cT3, zz[c], cT2), zz[c], cv), zz[c], cb);
        }
        d0 += dd[0]; d1 += dd[1]; d2 += dd[2];
        outv[i][0] = d0; outv[i][1] = d1; outv[i][2] = d2;
    }

    float q0 = d0 - acc.b[0], q1 = d1 - acc.b[1], q2 = d2 - acc.b[2];
    float e0 = wave_incl_scan(q0) - q0;
    float e1 = wave_incl_scan(q1) - q1;
    float e2 = wave_incl_scan(q2) - q2;
    float cor0 = x0 + e0, cor1 = x1 + e1, cor2 = x2 + e2;

    if (MODE == 2) {
        float4 s0a = { outv[0][0] + cor0, outv[1][0] + cor0, outv[2][0] + cor0, outv[3][0] + cor0 };
        float4 s0b = { outv[4][0] + cor0, outv[5][0] + cor0, outv[6][0] + cor0, outv[7][0] + cor0 };
        float4 s1a = { outv[0][1] + cor1, outv[1][1] + cor1, outv[2][1] + cor1, outv[3][1] + cor1 };
        float4 s1b = { outv[4][1] + cor1, outv[5][1] + cor1, outv[6][1] + cor1, outv[7][1] + cor1 };
        float4 s2a = { outv[0][2] + cor2, outv[1][2] + cor2, outv[2][2] + cor2, outv[3][2] + cor2 };
        float4 s2b = { outv[4][2] + cor2, outv[5][2] + cor2, outv[6][2] + cor2, outv[7][2] + cor2 };
        *(float4*)&xs[base]                   = s0a;
        *(float4*)&xs[base + 4]               = s0b;
        *(float4*)&xs[SEQ_LEN + base]         = s1a;
        *(float4*)&xs[SEQ_LEN + base + 4]     = s1b;
        *(float4*)&xs[2 * SEQ_LEN + base]     = s2a;
        *(float4*)&xs[2 * SEQ_LEN + base + 4] = s2b;
    } else {
        if (lane == 63) {
            float F0 = outv[M-1][0] + cor0;
            float F1 = outv[M-1][1] + cor1;
            float F2 = outv[M-1][2] + cor2;
            jf_w[3*g + 0] = float4{ acc.m[0], acc.m[1], acc.m[2], acc.m[3] };
            jf_w[3*g + 1] = float4{ acc.m[4], acc.m[5], acc.m[6], acc.m[7] };
            jf_w[3*g + 2] = float4{ acc.m[8], F0, F1, F2 };
        }
    }
}

// ---------- MLP (parallel, full GPU) ----------
__global__ __launch_bounds__(256) void mlp_kernel(
    const float* __restrict__ xs, const float* __restrict__ W1,
    const float* __restrict__ b1v, const float* __restrict__ W2,
    const float* __restrict__ b2v, float* __restrict__ out) {
    int s = blockIdx.x * 256 + threadIdx.x;
    float x0 = xs[s], x1 = xs[SEQ_LEN + s], x2 = xs[2 * SEQ_LEN + s];
    float acc0 = 0.f, acc1 = 0.f, acc2 = 0.f;
#pragma unroll 4
    for (int h = 0; h < HID; ++h) {
        float hv = fmaf(W1[3 * h + 0], x0,
                   fmaf(W1[3 * h + 1], x1,
                   fmaf(W1[3 * h + 2], x2, b1v[h])));
        hv = fmaxf(hv, 0.f);
        acc0 = fmaf(W2[h], hv, acc0);
        acc1 = fmaf(W2[HID + h], hv, acc1);
        acc2 = fmaf(W2[2 * HID + h], hv, acc2);
    }
    out[s] = acc0 + b2v[0];
    out[SEQ_LEN + s] = acc1 + b2v[1];
    out[2 * SEQ_LEN + s] = acc2 + b2v[2];
}

extern "C" void kernel_launch(void* const* d_in, const int* in_sizes, int n_in,
                              void* d_out, int out_size, void* d_ws, size_t ws_size,
                              hipStream_t stream) {
    const float* u  = (const float*)d_in[0];
    const float* dt = (const float*)d_in[1];
    const float* A  = (const float*)d_in[2];
    const float* B  = (const float*)d_in[3];
    const float* bA = (const float*)d_in[4];
    const float* W1 = (const float*)d_in[5];
    const float* b1 = (const float*)d_in[6];
    const float* W2 = (const float*)d_in[7];
    const float* b2 = (const float*)d_in[8];

    float* out  = (float*)d_out;
    float* memb = out + 3 * SEQ_LEN;

    float4* jfA = (float4*)d_ws;        // [NG*3] 24.6 KB
    float4* jfB = jfA + 3 * NG;         // [NG*3] 24.6 KB
    float4* xh  = jfB + 3 * NG;         // [NG]    8.2 KB

    // first shoot from xh=0 (writes jfA and xh=0)
    shootk<0><<<NG, 64, 0, stream>>>(u, A, dt, B, bA, nullptr, jfA, xh, nullptr);
    // NCORR-1 mid iterations: correct (from jf_r, xh) then shoot (to jf_w, xh)
    float4* rd = jfA;
    float4* wr = jfB;
    for (int j = 1; j < NCORR; ++j) {
        shootk<1><<<NG, 64, 0, stream>>>(u, A, dt, B, bA, rd, wr, xh, nullptr);
        float4* t = rd; rd = wr; wr = t;
    }
    // final: correct + shoot + store trajectory
    shootk<2><<<NG, 64, 0, stream>>>(u, A, dt, B, bA, rd, nullptr, xh, memb);
    mlp_kernel<<<SEQ_LEN / 256, 256, 0, stream>>>(memb, W1, b1, W2, b2, out);
}

// Round 9
// 121.842 us; speedup vs baseline: 6.8494x; 1.0557x over previous
//
#include <hip/hip_runtime.h>

#define SEQ_LEN 262144
#define K 512                      // steps per group (one wave per group)
#define M 8                        // steps per lane
#define NG (SEQ_LEN / K)           // 512 groups
#define NCORR 3                    // Newton corrections (err3 ~ 6e-4 << scheme err 7.8e-3)
#define HID 256
#define C2LE 2.885390081777927f    // 2*log2(e)

// ---------- DPP helpers ----------
template <int CTRL, int RM>
__device__ __forceinline__ float dpp_mov(float oldv, float v) {
    return __builtin_bit_cast(float, __builtin_amdgcn_update_dpp(
        __builtin_bit_cast(int, oldv), __builtin_bit_cast(int, v), CTRL, RM, 0xf, false));
}
template <int CTRL, int RM>
__device__ __forceinline__ float dpp_add(float v) {
    return v + dpp_mov<CTRL, RM>(0.0f, v);
}
__device__ __forceinline__ float wave_incl_scan(float v) {
    v = dpp_add<0x111, 0xf>(v);
    v = dpp_add<0x112, 0xf>(v);
    v = dpp_add<0x114, 0xf>(v);
    v = dpp_add<0x118, 0xf>(v);
    v = dpp_add<0x142, 0xa>(v);
    v = dpp_add<0x143, 0xc>(v);
    return v;
}
// full-wave shift right by 1 (lane i <- lane i-1; lane 0 <- 0)
__device__ __forceinline__ float dpp_wshr1(float v) {
    return __builtin_bit_cast(float, __builtin_amdgcn_update_dpp(
        0, __builtin_bit_cast(int, v), 0x138, 0xf, 0xf, false));
}
__device__ __forceinline__ float readlane_f(float v, int lane) {
    return __builtin_bit_cast(
        float, __builtin_amdgcn_readlane(__builtin_bit_cast(int, v), lane));
}

// ---------- affine map (3x3 M, 3 b) ----------
struct Aff { float m[9]; float b[3]; };

// r = n ∘ o  (apply o first, then n)
__device__ __forceinline__ void compose(Aff& r, const Aff& n, const Aff& o) {
#pragma unroll
    for (int i = 0; i < 3; ++i) {
#pragma unroll
        for (int j = 0; j < 3; ++j)
            r.m[3*i+j] = fmaf(n.m[3*i+0], o.m[0+j],
                         fmaf(n.m[3*i+1], o.m[3+j],
                              n.m[3*i+2] * o.m[6+j]));
        r.b[i] = fmaf(n.m[3*i+0], o.b[0],
                 fmaf(n.m[3*i+1], o.b[1],
                 fmaf(n.m[3*i+2], o.b[2], n.b[i])));
    }
}

template <int CTRL, int RM>
__device__ __forceinline__ void scan_level(Aff& a) {
    Aff p;
    p.m[0] = dpp_mov<CTRL, RM>(1.f, a.m[0]);
    p.m[1] = dpp_mov<CTRL, RM>(0.f, a.m[1]);
    p.m[2] = dpp_mov<CTRL, RM>(0.f, a.m[2]);
    p.m[3] = dpp_mov<CTRL, RM>(0.f, a.m[3]);
    p.m[4] = dpp_mov<CTRL, RM>(1.f, a.m[4]);
    p.m[5] = dpp_mov<CTRL, RM>(0.f, a.m[5]);
    p.m[6] = dpp_mov<CTRL, RM>(0.f, a.m[6]);
    p.m[7] = dpp_mov<CTRL, RM>(0.f, a.m[7]);
    p.m[8] = dpp_mov<CTRL, RM>(1.f, a.m[8]);
    p.b[0] = dpp_mov<CTRL, RM>(0.f, a.b[0]);
    p.b[1] = dpp_mov<CTRL, RM>(0.f, a.b[1]);
    p.b[2] = dpp_mov<CTRL, RM>(0.f, a.b[2]);
    Aff r; compose(r, a, p); a = r;
}

// MODE: 0 = FIRST (xh=0, no correct), 1 = MID (correct+shoot), 2 = STORE (correct+shoot+store)
template <int MODE>
__global__ __launch_bounds__(64) void shootk(
    const float* __restrict__ u,     // [3][S]
    const float* __restrict__ Am,    // [3][3]
    const float* __restrict__ dtp,   // scalar
    const float* __restrict__ Bm,    // [3][3]
    const float* __restrict__ bAp,   // [3]
    const float4* __restrict__ jf_r, // [NG*3] prev iteration's {J,F}
    float4* __restrict__ jf_w,       // [NG*3] this iteration's {J,F}
    float4* __restrict__ xh,         // [NG] group start states
    float* __restrict__ xs) {        // [3][S] membrane out
    const int lane = threadIdx.x;
    const int g = blockIdx.x;
    const float dt = dtp[0];
    const float invdt3 = 1.0f / (3.0f * dt);
    float a[9], as[9];
#pragma unroll
    for (int i = 0; i < 9; ++i) { a[i] = Am[i]; as[i] = C2LE * Am[i]; }

    // ---- build w for this block's slice in registers (from u) ----
    const int base = g * K + M * lane;
    float4 ua0 = *(const float4*)(u + base);
    float4 ua1 = *(const float4*)(u + base + 4);
    float4 ub0 = *(const float4*)(u + SEQ_LEN + base);
    float4 ub1 = *(const float4*)(u + SEQ_LEN + base + 4);
    float4 uc0 = *(const float4*)(u + 2 * SEQ_LEN + base);
    float4 uc1 = *(const float4*)(u + 2 * SEQ_LEN + base + 4);
    float B0 = Bm[0], B1 = Bm[1], B2 = Bm[2], B3 = Bm[3], B4 = Bm[4],
          B5 = Bm[5], B6 = Bm[6], B7 = Bm[7], B8 = Bm[8];
    float ba0 = bAp[0], ba1 = bAp[1], ba2 = bAp[2];
    float U0[M] = { ua0.x, ua0.y, ua0.z, ua0.w, ua1.x, ua1.y, ua1.z, ua1.w };
    float U1[M] = { ub0.x, ub0.y, ub0.z, ub0.w, ub1.x, ub1.y, ub1.z, ub1.w };
    float U2[M] = { uc0.x, uc0.y, uc0.z, uc0.w, uc1.x, uc1.y, uc1.z, uc1.w };
    float w0[M], w1[M], w2[M];
#pragma unroll
    for (int i = 0; i < M; ++i) {
        w0[i] = C2LE * fmaf(B0, U0[i], fmaf(B1, U1[i], fmaf(B2, U2[i], ba0)));
        w1[i] = C2LE * fmaf(B3, U0[i], fmaf(B4, U1[i], fmaf(B5, U2[i], ba1)));
        w2[i] = C2LE * fmaf(B6, U0[i], fmaf(B7, U1[i], fmaf(B8, U2[i], ba2)));
    }

    // ---- Newton correct (redundant per block) -> this block's start state ----
    float x0 = 0.f, x1 = 0.f, x2 = 0.f;
    if (MODE != 0) {
        float J[8][9], dv[8][3], xhn0[8], xhn1[8], xhn2[8];
#pragma unroll
        for (int i = 0; i < 8; ++i) {
            int gg = 8 * lane + i;
            float4 q0v = jf_r[3*gg + 0], q1v = jf_r[3*gg + 1], q2v = jf_r[3*gg + 2];
            J[i][0] = q0v.x; J[i][1] = q0v.y; J[i][2] = q0v.z; J[i][3] = q0v.w;
            J[i][4] = q1v.x; J[i][5] = q1v.y; J[i][6] = q1v.z; J[i][7] = q1v.w;
            J[i][8] = q2v.x;
            float xn0 = 0.f, xn1 = 0.f, xn2 = 0.f;
            if (gg < NG - 1) {                     // xh[gg+1]; group 511's end unused
                float4 xnv = xh[gg + 1];
                xn0 = xnv.x; xn1 = xnv.y; xn2 = xnv.z;
            }
            xhn0[i] = xn0; xhn1[i] = xn1; xhn2[i] = xn2;
            dv[i][0] = q2v.y - xn0;                // F_g - xh_old[g+1]
            dv[i][1] = q2v.z - xn1;
            dv[i][2] = q2v.w - xn2;
        }
        Aff c;
#pragma unroll
        for (int k = 0; k < 9; ++k) c.m[k] = J[0][k];
        c.b[0] = dv[0][0]; c.b[1] = dv[0][1]; c.b[2] = dv[0][2];
#pragma unroll
        for (int i = 1; i < 8; ++i) {
            Aff s;
#pragma unroll
            for (int k = 0; k < 9; ++k) s.m[k] = J[i][k];
            s.b[0] = dv[i][0]; s.b[1] = dv[i][1]; s.b[2] = dv[i][2];
            Aff r; compose(r, s, c); c = r;
        }
        scan_level<0x111, 0xf>(c);
        scan_level<0x112, 0xf>(c);
        scan_level<0x114, 0xf>(c);
        scan_level<0x118, 0xf>(c);
        scan_level<0x142, 0xa>(c);
        scan_level<0x143, 0xc>(c);
        float ce0 = dpp_wshr1(c.b[0]);             // e at group 8*lane
        float ce1 = dpp_wshr1(c.b[1]);
        float ce2 = dpp_wshr1(c.b[2]);
        // walk: e_{g+1} = d_g + J_g e_g ; xh_new[g+1] = xh_old[g+1] + e_{g+1}
#pragma unroll
        for (int i = 0; i < 8; ++i) {
            float n0 = fmaf(J[i][0], ce0, fmaf(J[i][1], ce1, fmaf(J[i][2], ce2, dv[i][0])));
            float n1 = fmaf(J[i][3], ce0, fmaf(J[i][4], ce1, fmaf(J[i][5], ce2, dv[i][1])));
            float n2 = fmaf(J[i][6], ce0, fmaf(J[i][7], ce1, fmaf(J[i][8], ce2, dv[i][2])));
            ce0 = n0; ce1 = n1; ce2 = n2;
            xhn0[i] += ce0; xhn1[i] += ce1; xhn2[i] += ce2;  // now xh_new[8l+i+1]
        }
        // broadcast xh_new[g] to the whole wave (g>0; g==0 stays 0)
        if (g > 0) {
            const int tl = (g - 1) >> 3, idx = (g - 1) & 7;  // wave-uniform
            float p0 = xhn0[0], p1 = xhn1[0], p2 = xhn2[0];
#pragma unroll
            for (int i = 1; i < 8; ++i) {
                p0 = (idx == i) ? xhn0[i] : p0;
                p1 = (idx == i) ? xhn1[i] : p1;
                p2 = (idx == i) ? xhn2[i] : p2;
            }
            x0 = readlane_f(p0, tl);
            x1 = readlane_f(p1, tl);
            x2 = readlane_f(p2, tl);
        }
    }
    // publish this block's (possibly updated) start state for the next correct
    if (MODE != 2 && lane == 0) xh[g] = float4{ x0, x1, x2, 0.f };

    // ---- shoot body (validated scheme) ----
    float zc0 = fmaf(as[0], x0, fmaf(as[1], x1, as[2] * x2));
    float zc1 = fmaf(as[3], x0, fmaf(as[4], x1, as[5] * x2));
    float zc2 = fmaf(as[6], x0, fmaf(as[7], x1, as[8] * x2));

    float t0s[M][3], c1s[M][3];
    Aff acc;
#pragma unroll
    for (int i = 0; i < M; ++i) {
        float z[3] = { w0[i] + zc0, w1[i] + zc1, w2[i] + zc2 };
        float cb[3], cv[3];
#pragma unroll
        for (int c = 0; c < 3; ++c) {
            float e  = __builtin_amdgcn_exp2f(z[c]);
            float r  = __builtin_amdgcn_rcpf(e + 1.0f);
            float t  = fmaf(-2.0f, r, 1.0f);
            float b  = dt * t;
            float c1 = fmaf(-b, t, dt);
            t0s[i][c] = t; c1s[i][c] = c1;
            cb[c] = b; cv[c] = c1;
        }
        Aff s;
        s.m[0] = fmaf(cv[0], a[0], 1.f); s.m[1] = cv[0] * a[1]; s.m[2] = cv[0] * a[2];
        s.m[3] = cv[1] * a[3]; s.m[4] = fmaf(cv[1], a[4], 1.f); s.m[5] = cv[1] * a[5];
        s.m[6] = cv[2] * a[6]; s.m[7] = cv[2] * a[7]; s.m[8] = fmaf(cv[2], a[8], 1.f);
        s.b[0] = cb[0]; s.b[1] = cb[1]; s.b[2] = cb[2];
        if (i == 0) acc = s;
        else { Aff r; compose(r, s, acc); acc = r; }
    }

    scan_level<0x111, 0xf>(acc);
    scan_level<0x112, 0xf>(acc);
    scan_level<0x114, 0xf>(acc);
    scan_level<0x118, 0xf>(acc);
    scan_level<0x142, 0xa>(acc);
    scan_level<0x143, 0xc>(acc);

    float ds0 = dpp_wshr1(acc.b[0]);
    float ds1 = dpp_wshr1(acc.b[1]);
    float ds2 = dpp_wshr1(acc.b[2]);

    float d0 = ds0, d1 = ds1, d2 = ds2;
    float outv[M][3];
#pragma unroll
    for (int i = 0; i < M; ++i) {
        float zz0 = fmaf(a[0], d0, fmaf(a[1], d1, a[2] * d2));
        float zz1 = fmaf(a[3], d0, fmaf(a[4], d1, a[5] * d2));
        float zz2 = fmaf(a[6], d0, fmaf(a[7], d1, a[8] * d2));
        float zz[3] = { zz0, zz1, zz2 };
        float dd[3];
#pragma unroll
        for (int c = 0; c < 3; ++c) {
            float t   = t0s[i][c], cv = c1s[i][c];
            float cb  = dt * t;
            float cT2 = -(t * cv);
            float pc  = fmaf(-invdt3, cv, 0.66666667f * (t * t));
            float cT3 = cv * pc;
            dd[c] = fmaf(fmaf(fmaf(cT3, zz[c], cT2), zz[c], cv), zz[c], cb);
        }
        d0 += dd[0]; d1 += dd[1]; d2 += dd[2];
        outv[i][0] = d0; outv[i][1] = d1; outv[i][2] = d2;
    }

    float q0 = d0 - acc.b[0], q1 = d1 - acc.b[1], q2 = d2 - acc.b[2];
    float e0 = wave_incl_scan(q0) - q0;
    float e1 = wave_incl_scan(q1) - q1;
    float e2 = wave_incl_scan(q2) - q2;
    float cor0 = x0 + e0, cor1 = x1 + e1, cor2 = x2 + e2;

    if (MODE == 2) {
        float4 s0a = { outv[0][0] + cor0, outv[1][0] + cor0, outv[2][0] + cor0, outv[3][0] + cor0 };
        float4 s0b = { outv[4][0] + cor0, outv[5][0] + cor0, outv[6][0] + cor0, outv[7][0] + cor0 };
        float4 s1a = { outv[0][1] + cor1, outv[1][1] + cor1, outv[2][1] + cor1, outv[3][1] + cor1 };
        float4 s1b = { outv[4][1] + cor1, outv[5][1] + cor1, outv[6][1] + cor1, outv[7][1] + cor1 };
        float4 s2a = { outv[0][2] + cor2, outv[1][2] + cor2, outv[2][2] + cor2, outv[3][2] + cor2 };
        float4 s2b = { outv[4][2] + cor2, outv[5][2] + cor2, outv[6][2] + cor2, outv[7][2] + cor2 };
        *(float4*)&xs[base]                   = s0a;
        *(float4*)&xs[base + 4]               = s0b;
        *(float4*)&xs[SEQ_LEN + base]         = s1a;
        *(float4*)&xs[SEQ_LEN + base + 4]     = s1b;
        *(float4*)&xs[2 * SEQ_LEN + base]     = s2a;
        *(float4*)&xs[2 * SEQ_LEN + base + 4] = s2b;
    } else {
        if (lane == 63) {
            float F0 = outv[M-1][0] + cor0;
            float F1 = outv[M-1][1] + cor1;
            float F2 = outv[M-1][2] + cor2;
            jf_w[3*g + 0] = float4{ acc.m[0], acc.m[1], acc.m[2], acc.m[3] };
            jf_w[3*g + 1] = float4{ acc.m[4], acc.m[5], acc.m[6], acc.m[7] };
            jf_w[3*g + 2] = float4{ acc.m[8], F0, F1, F2 };
        }
    }
}

// ---------- MLP (parallel, full GPU) ----------
__global__ __launch_bounds__(256) void mlp_kernel(
    const float* __restrict__ xs, const float* __restrict__ W1,
    const float* __restrict__ b1v, const float* __restrict__ W2,
    const float* __restrict__ b2v, float* __restrict__ out) {
    int s = blockIdx.x * 256 + threadIdx.x;
    float x0 = xs[s], x1 = xs[SEQ_LEN + s], x2 = xs[2 * SEQ_LEN + s];
    float acc0 = 0.f, acc1 = 0.f, acc2 = 0.f;
#pragma unroll 4
    for (int h = 0; h < HID; ++h) {
        float hv = fmaf(W1[3 * h + 0], x0,
                   fmaf(W1[3 * h + 1], x1,
                   fmaf(W1[3 * h + 2], x2, b1v[h])));
        hv = fmaxf(hv, 0.f);
        acc0 = fmaf(W2[h], hv, acc0);
        acc1 = fmaf(W2[HID + h], hv, acc1);
        acc2 = fmaf(W2[2 * HID + h], hv, acc2);
    }
    out[s] = acc0 + b2v[0];
    out[SEQ_LEN + s] = acc1 + b2v[1];
    out[2 * SEQ_LEN + s] = acc2 + b2v[2];
}

extern "C" void kernel_launch(void* const* d_in, const int* in_sizes, int n_in,
                              void* d_out, int out_size, void* d_ws, size_t ws_size,
                              hipStream_t stream) {
    const float* u  = (const float*)d_in[0];
    const float* dt = (const float*)d_in[1];
    const float* A  = (const float*)d_in[2];
    const float* B  = (const float*)d_in[3];
    const float* bA = (const float*)d_in[4];
    const float* W1 = (const float*)d_in[5];
    const float* b1 = (const float*)d_in[6];
    const float* W2 = (const float*)d_in[7];
    const float* b2 = (const float*)d_in[8];

    float* out  = (float*)d_out;
    float* memb = out + 3 * SEQ_LEN;

    float4* jfA = (float4*)d_ws;        // [NG*3] 24.6 KB
    float4* jfB = jfA + 3 * NG;         // [NG*3] 24.6 KB
    float4* xh  = jfB + 3 * NG;         // [NG]    8.2 KB

    // first shoot from xh=0 (writes jfA and xh=0)
    shootk<0><<<NG, 64, 0, stream>>>(u, A, dt, B, bA, nullptr, jfA, xh, nullptr);
    // NCORR-1 mid iterations: correct (from jf_r, xh) then shoot (to jf_w, xh)
    float4* rd = jfA;
    float4* wr = jfB;
    for (int j = 1; j < NCORR; ++j) {
        shootk<1><<<NG, 64, 0, stream>>>(u, A, dt, B, bA, rd, wr, xh, nullptr);
        float4* t = rd; rd = wr; wr = t;
    }
    // final: correct + shoot + store trajectory
    shootk<2><<<NG, 64, 0, stream>>>(u, A, dt, B, bA, rd, nullptr, xh, memb);
    mlp_kernel<<<SEQ_LEN / 256, 256, 0, stream>>>(memb, W1, b1, W2, b2, out);
}

// Round 10
// 113.057 us; speedup vs baseline: 7.3816x; 1.0777x over previous
//
#include <hip/hip_runtime.h>

#define SEQ_LEN 262144
#define K 512                      // steps per group (one wave per group)
#define M 8                        // steps per lane
#define NG (SEQ_LEN / K)           // 512 groups
#define NCORR 2                    // Newton corrections (err2 ~ 2e-6..2e-3 << threshold)
#define HID 256
#define C2LE 2.885390081777927f    // 2*log2(e)

// ---------- DPP helpers ----------
template <int CTRL, int RM>
__device__ __forceinline__ float dpp_mov(float oldv, float v) {
    return __builtin_bit_cast(float, __builtin_amdgcn_update_dpp(
        __builtin_bit_cast(int, oldv), __builtin_bit_cast(int, v), CTRL, RM, 0xf, false));
}
template <int CTRL, int RM>
__device__ __forceinline__ float dpp_add(float v) {
    return v + dpp_mov<CTRL, RM>(0.0f, v);
}
__device__ __forceinline__ float wave_incl_scan(float v) {
    v = dpp_add<0x111, 0xf>(v);
    v = dpp_add<0x112, 0xf>(v);
    v = dpp_add<0x114, 0xf>(v);
    v = dpp_add<0x118, 0xf>(v);
    v = dpp_add<0x142, 0xa>(v);
    v = dpp_add<0x143, 0xc>(v);
    return v;
}
// full-wave shift right by 1 (lane i <- lane i-1; lane 0 <- 0)
__device__ __forceinline__ float dpp_wshr1(float v) {
    return __builtin_bit_cast(float, __builtin_amdgcn_update_dpp(
        0, __builtin_bit_cast(int, v), 0x138, 0xf, 0xf, false));
}
__device__ __forceinline__ float readlane_f(float v, int lane) {
    return __builtin_bit_cast(
        float, __builtin_amdgcn_readlane(__builtin_bit_cast(int, v), lane));
}

// ---------- affine map (3x3 M, 3 b) ----------
struct Aff { float m[9]; float b[3]; };

// r = n ∘ o  (apply o first, then n)
__device__ __forceinline__ void compose(Aff& r, const Aff& n, const Aff& o) {
#pragma unroll
    for (int i = 0; i < 3; ++i) {
#pragma unroll
        for (int j = 0; j < 3; ++j)
            r.m[3*i+j] = fmaf(n.m[3*i+0], o.m[0+j],
                         fmaf(n.m[3*i+1], o.m[3+j],
                              n.m[3*i+2] * o.m[6+j]));
        r.b[i] = fmaf(n.m[3*i+0], o.b[0],
                 fmaf(n.m[3*i+1], o.b[1],
                 fmaf(n.m[3*i+2], o.b[2], n.b[i])));
    }
}

template <int CTRL, int RM>
__device__ __forceinline__ void scan_level(Aff& a) {
    Aff p;
    p.m[0] = dpp_mov<CTRL, RM>(1.f, a.m[0]);
    p.m[1] = dpp_mov<CTRL, RM>(0.f, a.m[1]);
    p.m[2] = dpp_mov<CTRL, RM>(0.f, a.m[2]);
    p.m[3] = dpp_mov<CTRL, RM>(0.f, a.m[3]);
    p.m[4] = dpp_mov<CTRL, RM>(1.f, a.m[4]);
    p.m[5] = dpp_mov<CTRL, RM>(0.f, a.m[5]);
    p.m[6] = dpp_mov<CTRL, RM>(0.f, a.m[6]);
    p.m[7] = dpp_mov<CTRL, RM>(0.f, a.m[7]);
    p.m[8] = dpp_mov<CTRL, RM>(1.f, a.m[8]);
    p.b[0] = dpp_mov<CTRL, RM>(0.f, a.b[0]);
    p.b[1] = dpp_mov<CTRL, RM>(0.f, a.b[1]);
    p.b[2] = dpp_mov<CTRL, RM>(0.f, a.b[2]);
    Aff r; compose(r, a, p); a = r;
}

// MODE: 0 = FIRST (xh=0, no correct), 1 = MID (correct+shoot), 2 = STORE (correct+shoot+store)
template <int MODE>
__global__ __launch_bounds__(64) void shootk(
    const float* __restrict__ u,     // [3][S]
    const float* __restrict__ Am,    // [3][3]
    const float* __restrict__ dtp,   // scalar
    const float* __restrict__ Bm,    // [3][3]
    const float* __restrict__ bAp,   // [3]
    const float4* __restrict__ jf_r, // [NG*3] prev iteration's {J,F}
    float4* __restrict__ jf_w,       // [NG*3] this iteration's {J,F}
    float4* __restrict__ xh,         // [NG] group start states
    float* __restrict__ xs) {        // [3][S] membrane out
    const int lane = threadIdx.x;
    const int g = blockIdx.x;
    const float dt = dtp[0];
    const float invdt3 = 1.0f / (3.0f * dt);
    float a[9], as[9];
#pragma unroll
    for (int i = 0; i < 9; ++i) { a[i] = Am[i]; as[i] = C2LE * Am[i]; }

    // ---- build w for this block's slice in registers (from u) ----
    const int base = g * K + M * lane;
    float4 ua0 = *(const float4*)(u + base);
    float4 ua1 = *(const float4*)(u + base + 4);
    float4 ub0 = *(const float4*)(u + SEQ_LEN + base);
    float4 ub1 = *(const float4*)(u + SEQ_LEN + base + 4);
    float4 uc0 = *(const float4*)(u + 2 * SEQ_LEN + base);
    float4 uc1 = *(const float4*)(u + 2 * SEQ_LEN + base + 4);
    float B0 = Bm[0], B1 = Bm[1], B2 = Bm[2], B3 = Bm[3], B4 = Bm[4],
          B5 = Bm[5], B6 = Bm[6], B7 = Bm[7], B8 = Bm[8];
    float ba0 = bAp[0], ba1 = bAp[1], ba2 = bAp[2];
    float U0[M] = { ua0.x, ua0.y, ua0.z, ua0.w, ua1.x, ua1.y, ua1.z, ua1.w };
    float U1[M] = { ub0.x, ub0.y, ub0.z, ub0.w, ub1.x, ub1.y, ub1.z, ub1.w };
    float U2[M] = { uc0.x, uc0.y, uc0.z, uc0.w, uc1.x, uc1.y, uc1.z, uc1.w };
    float w0[M], w1[M], w2[M];
#pragma unroll
    for (int i = 0; i < M; ++i) {
        w0[i] = C2LE * fmaf(B0, U0[i], fmaf(B1, U1[i], fmaf(B2, U2[i], ba0)));
        w1[i] = C2LE * fmaf(B3, U0[i], fmaf(B4, U1[i], fmaf(B5, U2[i], ba1)));
        w2[i] = C2LE * fmaf(B6, U0[i], fmaf(B7, U1[i], fmaf(B8, U2[i], ba2)));
    }

    // ---- Newton correct (redundant per block) -> this block's start state ----
    float x0 = 0.f, x1 = 0.f, x2 = 0.f;
    if (MODE != 0) {
        float J[8][9], dv[8][3], xhn0[8], xhn1[8], xhn2[8];
#pragma unroll
        for (int i = 0; i < 8; ++i) {
            int gg = 8 * lane + i;
            float4 q0v = jf_r[3*gg + 0], q1v = jf_r[3*gg + 1], q2v = jf_r[3*gg + 2];
            J[i][0] = q0v.x; J[i][1] = q0v.y; J[i][2] = q0v.z; J[i][3] = q0v.w;
            J[i][4] = q1v.x; J[i][5] = q1v.y; J[i][6] = q1v.z; J[i][7] = q1v.w;
            J[i][8] = q2v.x;
            float xn0 = 0.f, xn1 = 0.f, xn2 = 0.f;
            if (gg < NG - 1) {                     // xh[gg+1]; group 511's end unused
                float4 xnv = xh[gg + 1];
                xn0 = xnv.x; xn1 = xnv.y; xn2 = xnv.z;
            }
            xhn0[i] = xn0; xhn1[i] = xn1; xhn2[i] = xn2;
            dv[i][0] = q2v.y - xn0;                // F_g - xh_old[g+1]
            dv[i][1] = q2v.z - xn1;
            dv[i][2] = q2v.w - xn2;
        }
        Aff c;
#pragma unroll
        for (int k = 0; k < 9; ++k) c.m[k] = J[0][k];
        c.b[0] = dv[0][0]; c.b[1] = dv[0][1]; c.b[2] = dv[0][2];
#pragma unroll
        for (int i = 1; i < 8; ++i) {
            Aff s;
#pragma unroll
            for (int k = 0; k < 9; ++k) s.m[k] = J[i][k];
            s.b[0] = dv[i][0]; s.b[1] = dv[i][1]; s.b[2] = dv[i][2];
            Aff r; compose(r, s, c); c = r;
        }
        scan_level<0x111, 0xf>(c);
        scan_level<0x112, 0xf>(c);
        scan_level<0x114, 0xf>(c);
        scan_level<0x118, 0xf>(c);
        scan_level<0x142, 0xa>(c);
        scan_level<0x143, 0xc>(c);
        float ce0 = dpp_wshr1(c.b[0]);             // e at group 8*lane
        float ce1 = dpp_wshr1(c.b[1]);
        float ce2 = dpp_wshr1(c.b[2]);
        // walk: e_{g+1} = d_g + J_g e_g ; xh_new[g+1] = xh_old[g+1] + e_{g+1}
#pragma unroll
        for (int i = 0; i < 8; ++i) {
            float n0 = fmaf(J[i][0], ce0, fmaf(J[i][1], ce1, fmaf(J[i][2], ce2, dv[i][0])));
            float n1 = fmaf(J[i][3], ce0, fmaf(J[i][4], ce1, fmaf(J[i][5], ce2, dv[i][1])));
            float n2 = fmaf(J[i][6], ce0, fmaf(J[i][7], ce1, fmaf(J[i][8], ce2, dv[i][2])));
            ce0 = n0; ce1 = n1; ce2 = n2;
            xhn0[i] += ce0; xhn1[i] += ce1; xhn2[i] += ce2;  // now xh_new[8l+i+1]
        }
        // broadcast xh_new[g] to the whole wave (g>0; g==0 stays 0)
        if (g > 0) {
            const int tl = (g - 1) >> 3, idx = (g - 1) & 7;  // wave-uniform
            float p0 = xhn0[0], p1 = xhn1[0], p2 = xhn2[0];
#pragma unroll
            for (int i = 1; i < 8; ++i) {
                p0 = (idx == i) ? xhn0[i] : p0;
                p1 = (idx == i) ? xhn1[i] : p1;
                p2 = (idx == i) ? xhn2[i] : p2;
            }
            x0 = readlane_f(p0, tl);
            x1 = readlane_f(p1, tl);
            x2 = readlane_f(p2, tl);
        }
    }
    // publish this block's (possibly updated) start state for the next correct
    if (MODE != 2 && lane == 0) xh[g] = float4{ x0, x1, x2, 0.f };

    // ---- shoot body (validated scheme) ----
    float zc0 = fmaf(as[0], x0, fmaf(as[1], x1, as[2] * x2));
    float zc1 = fmaf(as[3], x0, fmaf(as[4], x1, as[5] * x2));
    float zc2 = fmaf(as[6], x0, fmaf(as[7], x1, as[8] * x2));

    float t0s[M][3], c1s[M][3];
    Aff acc;
#pragma unroll
    for (int i = 0; i < M; ++i) {
        float z[3] = { w0[i] + zc0, w1[i] + zc1, w2[i] + zc2 };
        float cb[3], cv[3];
#pragma unroll
        for (int c = 0; c < 3; ++c) {
            float e  = __builtin_amdgcn_exp2f(z[c]);
            float r  = __builtin_amdgcn_rcpf(e + 1.0f);
            float t  = fmaf(-2.0f, r, 1.0f);
            float b  = dt * t;
            float c1 = fmaf(-b, t, dt);
            t0s[i][c] = t; c1s[i][c] = c1;
            cb[c] = b; cv[c] = c1;
        }
        Aff s;
        s.m[0] = fmaf(cv[0], a[0], 1.f); s.m[1] = cv[0] * a[1]; s.m[2] = cv[0] * a[2];
        s.m[3] = cv[1] * a[3]; s.m[4] = fmaf(cv[1], a[4], 1.f); s.m[5] = cv[1] * a[5];
        s.m[6] = cv[2] * a[6]; s.m[7] = cv[2] * a[7]; s.m[8] = fmaf(cv[2], a[8], 1.f);
        s.b[0] = cb[0]; s.b[1] = cb[1]; s.b[2] = cb[2];
        if (i == 0) acc = s;
        else { Aff r; compose(r, s, acc); acc = r; }
    }

    scan_level<0x111, 0xf>(acc);
    scan_level<0x112, 0xf>(acc);
    scan_level<0x114, 0xf>(acc);
    scan_level<0x118, 0xf>(acc);
    scan_level<0x142, 0xa>(acc);
    scan_level<0x143, 0xc>(acc);

    float ds0 = dpp_wshr1(acc.b[0]);
    float ds1 = dpp_wshr1(acc.b[1]);
    float ds2 = dpp_wshr1(acc.b[2]);

    float d0 = ds0, d1 = ds1, d2 = ds2;
    float outv[M][3];
#pragma unroll
    for (int i = 0; i < M; ++i) {
        float zz0 = fmaf(a[0], d0, fmaf(a[1], d1, a[2] * d2));
        float zz1 = fmaf(a[3], d0, fmaf(a[4], d1, a[5] * d2));
        float zz2 = fmaf(a[6], d0, fmaf(a[7], d1, a[8] * d2));
        float zz[3] = { zz0, zz1, zz2 };
        float dd[3];
#pragma unroll
        for (int c = 0; c < 3; ++c) {
            float t   = t0s[i][c], cv = c1s[i][c];
            float cb  = dt * t;
            float cT2 = -(t * cv);
            float pc  = fmaf(-invdt3, cv, 0.66666667f * (t * t));
            float cT3 = cv * pc;
            dd[c] = fmaf(fmaf(fmaf(cT3, zz[c], cT2), zz[c], cv), zz[c], cb);
        }
        d0 += dd[0]; d1 += dd[1]; d2 += dd[2];
        outv[i][0] = d0; outv[i][1] = d1; outv[i][2] = d2;
    }

    float q0 = d0 - acc.b[0], q1 = d1 - acc.b[1], q2 = d2 - acc.b[2];
    float e0 = wave_incl_scan(q0) - q0;
    float e1 = wave_incl_scan(q1) - q1;
    float e2 = wave_incl_scan(q2) - q2;
    float cor0 = x0 + e0, cor1 = x1 + e1, cor2 = x2 + e2;

    if (MODE == 2) {
        float4 s0a = { outv[0][0] + cor0, outv[1][0] + cor0, outv[2][0] + cor0, outv[3][0] + cor0 };
        float4 s0b = { outv[4][0] + cor0, outv[5][0] + cor0, outv[6][0] + cor0, outv[7][0] + cor0 };
        float4 s1a = { outv[0][1] + cor1, outv[1][1] + cor1, outv[2][1] + cor1, outv[3][1] + cor1 };
        float4 s1b = { outv[4][1] + cor1, outv[5][1] + cor1, outv[6][1] + cor1, outv[7][1] + cor1 };
        float4 s2a = { outv[0][2] + cor2, outv[1][2] + cor2, outv[2][2] + cor2, outv[3][2] + cor2 };
        float4 s2b = { outv[4][2] + cor2, outv[5][2] + cor2, outv[6][2] + cor2, outv[7][2] + cor2 };
        *(float4*)&xs[base]                   = s0a;
        *(float4*)&xs[base + 4]               = s0b;
        *(float4*)&xs[SEQ_LEN + base]         = s1a;
        *(float4*)&xs[SEQ_LEN + base + 4]     = s1b;
        *(float4*)&xs[2 * SEQ_LEN + base]     = s2a;
        *(float4*)&xs[2 * SEQ_LEN + base + 4] = s2b;
    } else {
        if (lane == 63) {
            float F0 = outv[M-1][0] + cor0;
            float F1 = outv[M-1][1] + cor1;
            float F2 = outv[M-1][2] + cor2;
            jf_w[3*g + 0] = float4{ acc.m[0], acc.m[1], acc.m[2], acc.m[3] };
            jf_w[3*g + 1] = float4{ acc.m[4], acc.m[5], acc.m[6], acc.m[7] };
            jf_w[3*g + 2] = float4{ acc.m[8], F0, F1, F2 };
        }
    }
}

// ---------- MLP (parallel, full GPU) ----------
__global__ __launch_bounds__(256) void mlp_kernel(
    const float* __restrict__ xs, const float* __restrict__ W1,
    const float* __restrict__ b1v, const float* __restrict__ W2,
    const float* __restrict__ b2v, float* __restrict__ out) {
    int s = blockIdx.x * 256 + threadIdx.x;
    float x0 = xs[s], x1 = xs[SEQ_LEN + s], x2 = xs[2 * SEQ_LEN + s];
    float acc0 = 0.f, acc1 = 0.f, acc2 = 0.f;
#pragma unroll 4
    for (int h = 0; h < HID; ++h) {
        float hv = fmaf(W1[3 * h + 0], x0,
                   fmaf(W1[3 * h + 1], x1,
                   fmaf(W1[3 * h + 2], x2, b1v[h])));
        hv = fmaxf(hv, 0.f);
        acc0 = fmaf(W2[h], hv, acc0);
        acc1 = fmaf(W2[HID + h], hv, acc1);
        acc2 = fmaf(W2[2 * HID + h], hv, acc2);
    }
    out[s] = acc0 + b2v[0];
    out[SEQ_LEN + s] = acc1 + b2v[1];
    out[2 * SEQ_LEN + s] = acc2 + b2v[2];
}

extern "C" void kernel_launch(void* const* d_in, const int* in_sizes, int n_in,
                              void* d_out, int out_size, void* d_ws, size_t ws_size,
                              hipStream_t stream) {
    const float* u  = (const float*)d_in[0];
    const float* dt = (const float*)d_in[1];
    const float* A  = (const float*)d_in[2];
    const float* B  = (const float*)d_in[3];
    const float* bA = (const float*)d_in[4];
    const float* W1 = (const float*)d_in[5];
    const float* b1 = (const float*)d_in[6];
    const float* W2 = (const float*)d_in[7];
    const float* b2 = (const float*)d_in[8];

    float* out  = (float*)d_out;
    float* memb = out + 3 * SEQ_LEN;

    float4* jfA = (float4*)d_ws;        // [NG*3] 24.6 KB
    float4* jfB = jfA + 3 * NG;         // [NG*3] 24.6 KB
    float4* xh  = jfB + 3 * NG;         // [NG]    8.2 KB

    // first shoot from xh=0 (writes jfA and xh=0)
    shootk<0><<<NG, 64, 0, stream>>>(u, A, dt, B, bA, nullptr, jfA, xh, nullptr);
    // NCORR-1 mid iterations: correct (from jf_r, xh) then shoot (to jf_w, xh)
    float4* rd = jfA;
    float4* wr = jfB;
    for (int j = 1; j < NCORR; ++j) {
        shootk<1><<<NG, 64, 0, stream>>>(u, A, dt, B, bA, rd, wr, xh, nullptr);
        float4* t = rd; rd = wr; wr = t;
    }
    // final: correct + shoot + store trajectory
    shootk<2><<<NG, 64, 0, stream>>>(u, A, dt, B, bA, rd, nullptr, xh, memb);
    mlp_kernel<<<SEQ_LEN / 256, 256, 0, stream>>>(memb, W1, b1, W2, b2, out);
}

// Round 12
// 112.492 us; speedup vs baseline: 7.4187x; 1.0050x over previous
//
#include <hip/hip_runtime.h>

#define SEQ_LEN 262144
#define K 512                      // steps per group (one wave per group)
#define M 8                        // steps per lane
#define NG (SEQ_LEN / K)           // 512 groups
#define NCORR 2                    // Newton corrections (NCORR=1 FAILS: absmax 3.6e-2 measured R11)
#define HID 256
#define C2LE 2.885390081777927f    // 2*log2(e)

// ---------- DPP helpers ----------
template <int CTRL, int RM>
__device__ __forceinline__ float dpp_mov(float oldv, float v) {
    return __builtin_bit_cast(float, __builtin_amdgcn_update_dpp(
        __builtin_bit_cast(int, oldv), __builtin_bit_cast(int, v), CTRL, RM, 0xf, false));
}
template <int CTRL, int RM>
__device__ __forceinline__ float dpp_add(float v) {
    return v + dpp_mov<CTRL, RM>(0.0f, v);
}
__device__ __forceinline__ float wave_incl_scan(float v) {
    v = dpp_add<0x111, 0xf>(v);
    v = dpp_add<0x112, 0xf>(v);
    v = dpp_add<0x114, 0xf>(v);
    v = dpp_add<0x118, 0xf>(v);
    v = dpp_add<0x142, 0xa>(v);
    v = dpp_add<0x143, 0xc>(v);
    return v;
}
// full-wave shift right by 1 (lane i <- lane i-1; lane 0 <- 0)
__device__ __forceinline__ float dpp_wshr1(float v) {
    return __builtin_bit_cast(float, __builtin_amdgcn_update_dpp(
        0, __builtin_bit_cast(int, v), 0x138, 0xf, 0xf, false));
}
__device__ __forceinline__ float readlane_f(float v, int lane) {
    return __builtin_bit_cast(
        float, __builtin_amdgcn_readlane(__builtin_bit_cast(int, v), lane));
}

// ---------- affine map (3x3 M, 3 b) ----------
struct Aff { float m[9]; float b[3]; };

// r = n ∘ o  (apply o first, then n)
__device__ __forceinline__ void compose(Aff& r, const Aff& n, const Aff& o) {
#pragma unroll
    for (int i = 0; i < 3; ++i) {
#pragma unroll
        for (int j = 0; j < 3; ++j)
            r.m[3*i+j] = fmaf(n.m[3*i+0], o.m[0+j],
                         fmaf(n.m[3*i+1], o.m[3+j],
                              n.m[3*i+2] * o.m[6+j]));
        r.b[i] = fmaf(n.m[3*i+0], o.b[0],
                 fmaf(n.m[3*i+1], o.b[1],
                 fmaf(n.m[3*i+2], o.b[2], n.b[i])));
    }
}

template <int CTRL, int RM>
__device__ __forceinline__ void scan_level(Aff& a) {
    Aff p;
    p.m[0] = dpp_mov<CTRL, RM>(1.f, a.m[0]);
    p.m[1] = dpp_mov<CTRL, RM>(0.f, a.m[1]);
    p.m[2] = dpp_mov<CTRL, RM>(0.f, a.m[2]);
    p.m[3] = dpp_mov<CTRL, RM>(0.f, a.m[3]);
    p.m[4] = dpp_mov<CTRL, RM>(1.f, a.m[4]);
    p.m[5] = dpp_mov<CTRL, RM>(0.f, a.m[5]);
    p.m[6] = dpp_mov<CTRL, RM>(0.f, a.m[6]);
    p.m[7] = dpp_mov<CTRL, RM>(0.f, a.m[7]);
    p.m[8] = dpp_mov<CTRL, RM>(1.f, a.m[8]);
    p.b[0] = dpp_mov<CTRL, RM>(0.f, a.b[0]);
    p.b[1] = dpp_mov<CTRL, RM>(0.f, a.b[1]);
    p.b[2] = dpp_mov<CTRL, RM>(0.f, a.b[2]);
    Aff r; compose(r, a, p); a = r;
}

// MODE: 0 = FIRST (xh=0, no correct), 1 = MID (correct+shoot), 2 = STORE (correct+shoot+store)
template <int MODE>
__global__ __launch_bounds__(64) void shootk(
    const float* __restrict__ u,     // [3][S]
    const float* __restrict__ Am,    // [3][3]
    const float* __restrict__ dtp,   // scalar
    const float* __restrict__ Bm,    // [3][3]
    const float* __restrict__ bAp,   // [3]
    const float4* __restrict__ jf_r, // [NG*3] prev iteration's {J,F}
    float4* __restrict__ jf_w,       // [NG*3] this iteration's {J,F}
    float4* __restrict__ xh,         // [NG] group start states
    float* __restrict__ xs) {        // [3][S] membrane out
    const int lane = threadIdx.x;
    const int g = blockIdx.x;
    const float dt = dtp[0];
    const float invdt3 = 1.0f / (3.0f * dt);
    float a[9], as[9];
#pragma unroll
    for (int i = 0; i < 9; ++i) { a[i] = Am[i]; as[i] = C2LE * Am[i]; }

    // ---- build w for this block's slice in registers (from u) ----
    const int base = g * K + M * lane;
    float4 ua0 = *(const float4*)(u + base);
    float4 ua1 = *(const float4*)(u + base + 4);
    float4 ub0 = *(const float4*)(u + SEQ_LEN + base);
    float4 ub1 = *(const float4*)(u + SEQ_LEN + base + 4);
    float4 uc0 = *(const float4*)(u + 2 * SEQ_LEN + base);
    float4 uc1 = *(const float4*)(u + 2 * SEQ_LEN + base + 4);
    float B0 = Bm[0], B1 = Bm[1], B2 = Bm[2], B3 = Bm[3], B4 = Bm[4],
          B5 = Bm[5], B6 = Bm[6], B7 = Bm[7], B8 = Bm[8];
    float ba0 = bAp[0], ba1 = bAp[1], ba2 = bAp[2];
    float U0[M] = { ua0.x, ua0.y, ua0.z, ua0.w, ua1.x, ua1.y, ua1.z, ua1.w };
    float U1[M] = { ub0.x, ub0.y, ub0.z, ub0.w, ub1.x, ub1.y, ub1.z, ub1.w };
    float U2[M] = { uc0.x, uc0.y, uc0.z, uc0.w, uc1.x, uc1.y, uc1.z, uc1.w };
    float w0[M], w1[M], w2[M];
#pragma unroll
    for (int i = 0; i < M; ++i) {
        w0[i] = C2LE * fmaf(B0, U0[i], fmaf(B1, U1[i], fmaf(B2, U2[i], ba0)));
        w1[i] = C2LE * fmaf(B3, U0[i], fmaf(B4, U1[i], fmaf(B5, U2[i], ba1)));
        w2[i] = C2LE * fmaf(B6, U0[i], fmaf(B7, U1[i], fmaf(B8, U2[i], ba2)));
    }

    // ---- Newton correct (redundant per block) -> this block's start state ----
    float x0 = 0.f, x1 = 0.f, x2 = 0.f;
    if (MODE != 0) {
        float J[8][9], dv[8][3], xhn0[8], xhn1[8], xhn2[8];
#pragma unroll
        for (int i = 0; i < 8; ++i) {
            int gg = 8 * lane + i;
            float4 q0v = jf_r[3*gg + 0], q1v = jf_r[3*gg + 1], q2v = jf_r[3*gg + 2];
            J[i][0] = q0v.x; J[i][1] = q0v.y; J[i][2] = q0v.z; J[i][3] = q0v.w;
            J[i][4] = q1v.x; J[i][5] = q1v.y; J[i][6] = q1v.z; J[i][7] = q1v.w;
            J[i][8] = q2v.x;
            float xn0 = 0.f, xn1 = 0.f, xn2 = 0.f;
            if (gg < NG - 1) {                     // xh[gg+1]; group 511's end unused
                float4 xnv = xh[gg + 1];
                xn0 = xnv.x; xn1 = xnv.y; xn2 = xnv.z;
            }
            xhn0[i] = xn0; xhn1[i] = xn1; xhn2[i] = xn2;
            dv[i][0] = q2v.y - xn0;                // F_g - xh_old[g+1]
            dv[i][1] = q2v.z - xn1;
            dv[i][2] = q2v.w - xn2;
        }
        Aff c;
#pragma unroll
        for (int k = 0; k < 9; ++k) c.m[k] = J[0][k];
        c.b[0] = dv[0][0]; c.b[1] = dv[0][1]; c.b[2] = dv[0][2];
#pragma unroll
        for (int i = 1; i < 8; ++i) {
            Aff s;
#pragma unroll
            for (int k = 0; k < 9; ++k) s.m[k] = J[i][k];
            s.b[0] = dv[i][0]; s.b[1] = dv[i][1]; s.b[2] = dv[i][2];
            Aff r; compose(r, s, c); c = r;
        }
        scan_level<0x111, 0xf>(c);
        scan_level<0x112, 0xf>(c);
        scan_level<0x114, 0xf>(c);
        scan_level<0x118, 0xf>(c);
        scan_level<0x142, 0xa>(c);
        scan_level<0x143, 0xc>(c);
        float ce0 = dpp_wshr1(c.b[0]);             // e at group 8*lane
        float ce1 = dpp_wshr1(c.b[1]);
        float ce2 = dpp_wshr1(c.b[2]);
        // walk: e_{g+1} = d_g + J_g e_g ; xh_new[g+1] = xh_old[g+1] + e_{g+1}
#pragma unroll
        for (int i = 0; i < 8; ++i) {
            float n0 = fmaf(J[i][0], ce0, fmaf(J[i][1], ce1, fmaf(J[i][2], ce2, dv[i][0])));
            float n1 = fmaf(J[i][3], ce0, fmaf(J[i][4], ce1, fmaf(J[i][5], ce2, dv[i][1])));
            float n2 = fmaf(J[i][6], ce0, fmaf(J[i][7], ce1, fmaf(J[i][8], ce2, dv[i][2])));
            ce0 = n0; ce1 = n1; ce2 = n2;
            xhn0[i] += ce0; xhn1[i] += ce1; xhn2[i] += ce2;  // now xh_new[8l+i+1]
        }
        // broadcast xh_new[g] to the whole wave (g>0; g==0 stays 0)
        if (g > 0) {
            const int tl = (g - 1) >> 3, idx = (g - 1) & 7;  // wave-uniform
            float p0 = xhn0[0], p1 = xhn1[0], p2 = xhn2[0];
#pragma unroll
            for (int i = 1; i < 8; ++i) {
                p0 = (idx == i) ? xhn0[i] : p0;
                p1 = (idx == i) ? xhn1[i] : p1;
                p2 = (idx == i) ? xhn2[i] : p2;
            }
            x0 = readlane_f(p0, tl);
            x1 = readlane_f(p1, tl);
            x2 = readlane_f(p2, tl);
        }
    }
    // publish this block's (possibly updated) start state for the next correct
    if (MODE != 2 && lane == 0) xh[g] = float4{ x0, x1, x2, 0.f };

    // ---- shoot body (validated scheme) ----
    float zc0 = fmaf(as[0], x0, fmaf(as[1], x1, as[2] * x2));
    float zc1 = fmaf(as[3], x0, fmaf(as[4], x1, as[5] * x2));
    float zc2 = fmaf(as[6], x0, fmaf(as[7], x1, as[8] * x2));

    float t0s[M][3], c1s[M][3];
    Aff acc;
#pragma unroll
    for (int i = 0; i < M; ++i) {
        float z[3] = { w0[i] + zc0, w1[i] + zc1, w2[i] + zc2 };
        float cb[3], cv[3];
#pragma unroll
        for (int c = 0; c < 3; ++c) {
            float e  = __builtin_amdgcn_exp2f(z[c]);
            float r  = __builtin_amdgcn_rcpf(e + 1.0f);
            float t  = fmaf(-2.0f, r, 1.0f);
            float b  = dt * t;
            float c1 = fmaf(-b, t, dt);
            t0s[i][c] = t; c1s[i][c] = c1;
            cb[c] = b; cv[c] = c1;
        }
        Aff s;
        s.m[0] = fmaf(cv[0], a[0], 1.f); s.m[1] = cv[0] * a[1]; s.m[2] = cv[0] * a[2];
        s.m[3] = cv[1] * a[3]; s.m[4] = fmaf(cv[1], a[4], 1.f); s.m[5] = cv[1] * a[5];
        s.m[6] = cv[2] * a[6]; s.m[7] = cv[2] * a[7]; s.m[8] = fmaf(cv[2], a[8], 1.f);
        s.b[0] = cb[0]; s.b[1] = cb[1]; s.b[2] = cb[2];
        if (i == 0) acc = s;
        else { Aff r; compose(r, s, acc); acc = r; }
    }

    scan_level<0x111, 0xf>(acc);
    scan_level<0x112, 0xf>(acc);
    scan_level<0x114, 0xf>(acc);
    scan_level<0x118, 0xf>(acc);
    scan_level<0x142, 0xa>(acc);
    scan_level<0x143, 0xc>(acc);

    float ds0 = dpp_wshr1(acc.b[0]);
    float ds1 = dpp_wshr1(acc.b[1]);
    float ds2 = dpp_wshr1(acc.b[2]);

    float d0 = ds0, d1 = ds1, d2 = ds2;
    float outv[M][3];
#pragma unroll
    for (int i = 0; i < M; ++i) {
        float zz0 = fmaf(a[0], d0, fmaf(a[1], d1, a[2] * d2));
        float zz1 = fmaf(a[3], d0, fmaf(a[4], d1, a[5] * d2));
        float zz2 = fmaf(a[6], d0, fmaf(a[7], d1, a[8] * d2));
        float zz[3] = { zz0, zz1, zz2 };
        float dd[3];
#pragma unroll
        for (int c = 0; c < 3; ++c) {
            float t   = t0s[i][c], cv = c1s[i][c];
            float cb  = dt * t;
            float cT2 = -(t * cv);
            float pc  = fmaf(-invdt3, cv, 0.66666667f * (t * t));
            float cT3 = cv * pc;
            dd[c] = fmaf(fmaf(fmaf(cT3, zz[c], cT2), zz[c], cv), zz[c], cb);
        }
        d0 += dd[0]; d1 += dd[1]; d2 += dd[2];
        outv[i][0] = d0; outv[i][1] = d1; outv[i][2] = d2;
    }

    float q0 = d0 - acc.b[0], q1 = d1 - acc.b[1], q2 = d2 - acc.b[2];
    float e0 = wave_incl_scan(q0) - q0;
    float e1 = wave_incl_scan(q1) - q1;
    float e2 = wave_incl_scan(q2) - q2;
    float cor0 = x0 + e0, cor1 = x1 + e1, cor2 = x2 + e2;

    if (MODE == 2) {
        float4 s0a = { outv[0][0] + cor0, outv[1][0] + cor0, outv[2][0] + cor0, outv[3][0] + cor0 };
        float4 s0b = { outv[4][0] + cor0, outv[5][0] + cor0, outv[6][0] + cor0, outv[7][0] + cor0 };
        float4 s1a = { outv[0][1] + cor1, outv[1][1] + cor1, outv[2][1] + cor1, outv[3][1] + cor1 };
        float4 s1b = { outv[4][1] + cor1, outv[5][1] + cor1, outv[6][1] + cor1, outv[7][1] + cor1 };
        float4 s2a = { outv[0][2] + cor2, outv[1][2] + cor2, outv[2][2] + cor2, outv[3][2] + cor2 };
        float4 s2b = { outv[4][2] + cor2, outv[5][2] + cor2, outv[6][2] + cor2, outv[7][2] + cor2 };
        *(float4*)&xs[base]                   = s0a;
        *(float4*)&xs[base + 4]               = s0b;
        *(float4*)&xs[SEQ_LEN + base]         = s1a;
        *(float4*)&xs[SEQ_LEN + base + 4]     = s1b;
        *(float4*)&xs[2 * SEQ_LEN + base]     = s2a;
        *(float4*)&xs[2 * SEQ_LEN + base + 4] = s2b;
    } else {
        if (lane == 63) {
            float F0 = outv[M-1][0] + cor0;
            float F1 = outv[M-1][1] + cor1;
            float F2 = outv[M-1][2] + cor2;
            jf_w[3*g + 0] = float4{ acc.m[0], acc.m[1], acc.m[2], acc.m[3] };
            jf_w[3*g + 1] = float4{ acc.m[4], acc.m[5], acc.m[6], acc.m[7] };
            jf_w[3*g + 2] = float4{ acc.m[8], F0, F1, F2 };
        }
    }
}

// ---------- MLP (parallel, full GPU) ----------
__global__ __launch_bounds__(256) void mlp_kernel(
    const float* __restrict__ xs, const float* __restrict__ W1,
    const float* __restrict__ b1v, const float* __restrict__ W2,
    const float* __restrict__ b2v, float* __restrict__ out) {
    int s = blockIdx.x * 256 + threadIdx.x;
    float x0 = xs[s], x1 = xs[SEQ_LEN + s], x2 = xs[2 * SEQ_LEN + s];
    float acc0 = 0.f, acc1 = 0.f, acc2 = 0.f;
#pragma unroll 4
    for (int h = 0; h < HID; ++h) {
        float hv = fmaf(W1[3 * h + 0], x0,
                   fmaf(W1[3 * h + 1], x1,
                   fmaf(W1[3 * h + 2], x2, b1v[h])));
        hv = fmaxf(hv, 0.f);
        acc0 = fmaf(W2[h], hv, acc0);
        acc1 = fmaf(W2[HID + h], hv, acc1);
        acc2 = fmaf(W2[2 * HID + h], hv, acc2);
    }
    out[s] = acc0 + b2v[0];
    out[SEQ_LEN + s] = acc1 + b2v[1];
    out[2 * SEQ_LEN + s] = acc2 + b2v[2];
}

extern "C" void kernel_launch(void* const* d_in, const int* in_sizes, int n_in,
                              void* d_out, int out_size, void* d_ws, size_t ws_size,
                              hipStream_t stream) {
    const float* u  = (const float*)d_in[0];
    const float* dt = (const float*)d_in[1];
    const float* A  = (const float*)d_in[2];
    const float* B  = (const float*)d_in[3];
    const float* bA = (const float*)d_in[4];
    const float* W1 = (const float*)d_in[5];
    const float* b1 = (const float*)d_in[6];
    const float* W2 = (const float*)d_in[7];
    const float* b2 = (const float*)d_in[8];

    float* out  = (float*)d_out;
    float* memb = out + 3 * SEQ_LEN;

    float4* jfA = (float4*)d_ws;        // [NG*3] 24.6 KB
    float4* jfB = jfA + 3 * NG;         // [NG*3] 24.6 KB
    float4* xh  = jfB + 3 * NG;         // [NG]    8.2 KB

    // first shoot from xh=0 (writes jfA and xh=0)
    shootk<0><<<NG, 64, 0, stream>>>(u, A, dt, B, bA, nullptr, jfA, xh, nullptr);
    // NCORR-1 mid iterations: correct (from jf_r, xh) then shoot (to jf_w, xh)
    float4* rd = jfA;
    float4* wr = jfB;
    for (int j = 1; j < NCORR; ++j) {
        shootk<1><<<NG, 64, 0, stream>>>(u, A, dt, B, bA, rd, wr, xh, nullptr);
        float4* t = rd; rd = wr; wr = t;
    }
    // final: correct + shoot + store trajectory
    shootk<2><<<NG, 64, 0, stream>>>(u, A, dt, B, bA, rd, nullptr, xh, memb);
    mlp_kernel<<<SEQ_LEN / 256, 256, 0, stream>>>(memb, W1, b1, W2, b2, out);
}